// Round 1
// baseline (4506.185 us; speedup 1.0000x reference)
//
#include <hip/hip_runtime.h>
#include <cstdint>

#define SEQ 2048
#define BATCH 2
#define TOK (BATCH * SEQ)      // 4096 tokens
#define HID 2048
#define NH 16
#define NKV 8
#define HD 128
#define QKV_LD 4096            // P buffer row: [q 2048 | k 1024 | v 1024]

// ---------------------------------------------------------------------------
// SGEMM (fp32): C[m][coff + n] = sum_k A[m][k] * W[n][k]
// A: [M x K] row-major (lda == K), W: [N x K] row-major (both K-contiguous).
// Tile 128x128, BK=16, 256 threads, 8x8 micro-tile per thread.
// ---------------------------------------------------------------------------
__global__ __launch_bounds__(256) void sgemm_bt(
    const float* __restrict__ A, const float* __restrict__ W,
    float* __restrict__ C, int K, int ldc, int coff)
{
    __shared__ float As[16][129];   // +1 pad: transpose-store bank spread
    __shared__ float Ws[16][129];

    const int tid = threadIdx.x;
    const int tx = tid & 15, ty = tid >> 4;
    const int bn = blockIdx.x, bm = blockIdx.y;

    float acc[8][8];
#pragma unroll
    for (int i = 0; i < 8; ++i)
#pragma unroll
        for (int j = 0; j < 8; ++j) acc[i][j] = 0.f;

    const float* Ab = A + (size_t)bm * 128 * K;
    const float* Wb = W + (size_t)bn * 128 * K;

    const int m0  = tid >> 2;         // 0..63
    const int kk0 = (tid & 3) * 4;    // 0,4,8,12

    for (int k0 = 0; k0 < K; k0 += 16) {
#pragma unroll
        for (int r = 0; r < 2; ++r) {
            const int m = m0 + r * 64;
            float4 a = *(const float4*)(Ab + (size_t)m * K + k0 + kk0);
            As[kk0 + 0][m] = a.x; As[kk0 + 1][m] = a.y;
            As[kk0 + 2][m] = a.z; As[kk0 + 3][m] = a.w;
            float4 w = *(const float4*)(Wb + (size_t)m * K + k0 + kk0);
            Ws[kk0 + 0][m] = w.x; Ws[kk0 + 1][m] = w.y;
            Ws[kk0 + 2][m] = w.z; Ws[kk0 + 3][m] = w.w;
        }
        __syncthreads();
#pragma unroll
        for (int kk = 0; kk < 16; ++kk) {
            float a[8], b[8];
#pragma unroll
            for (int i = 0; i < 8; ++i) a[i] = As[kk][ty * 8 + i];
#pragma unroll
            for (int j = 0; j < 8; ++j) b[j] = Ws[kk][tx * 8 + j];
#pragma unroll
            for (int i = 0; i < 8; ++i)
#pragma unroll
                for (int j = 0; j < 8; ++j) acc[i][j] += a[i] * b[j];
        }
        __syncthreads();
    }

    float* Cb = C + (size_t)(bm * 128) * ldc + coff + bn * 128;
#pragma unroll
    for (int i = 0; i < 8; ++i) {
        float* row = Cb + (size_t)(ty * 8 + i) * ldc + tx * 8;
        *(float4*)(row)     = make_float4(acc[i][0], acc[i][1], acc[i][2], acc[i][3]);
        *(float4*)(row + 4) = make_float4(acc[i][4], acc[i][5], acc[i][6], acc[i][7]);
    }
}

// ---------------------------------------------------------------------------
// Fused RMS-norm (per head, over 128 dims) + RoPE for q and k rows of P.
// Block = 256 threads = 4 waves; each wave handles one head-row of one token.
// grid = (6, TOK): blockIdx.x*4+wave = head-slot 0..23 (0..15 q, 16..23 k).
// ---------------------------------------------------------------------------
__global__ __launch_bounds__(256) void norm_rope(
    float* __restrict__ P, const float* __restrict__ cosb,
    const float* __restrict__ sinb, const float* __restrict__ qw,
    const float* __restrict__ kw)
{
    const int t    = blockIdx.y;            // token index = b*SEQ + s
    const int wave = threadIdx.x >> 6;
    const int lane = threadIdx.x & 63;
    const int hid  = blockIdx.x * 4 + wave; // 0..23

    float* ptr;
    const float* w;
    if (hid < NH) { ptr = P + (size_t)t * QKV_LD + hid * HD;              w = qw; }
    else          { ptr = P + (size_t)t * QKV_LD + HID + (hid - NH) * HD; w = kw; }

    float x1 = ptr[lane];
    float x2 = ptr[lane + 64];
    float ss = x1 * x1 + x2 * x2;
#pragma unroll
    for (int off = 1; off < 64; off <<= 1) ss += __shfl_xor(ss, off);
    const float r = rsqrtf(ss * (1.f / 128.f) + 1e-6f);
    const float n1 = x1 * r * w[lane];
    const float n2 = x2 * r * w[lane + 64];

    const float* cp = cosb + (size_t)t * HD;
    const float* sp = sinb + (size_t)t * HD;
    const float c1 = cp[lane], c2 = cp[lane + 64];
    const float s1 = sp[lane], s2 = sp[lane + 64];
    // rotate_half: out[d<64] = n1*c - n2*s ; out[d>=64] = n2*c + n1*s
    ptr[lane]      = n1 * c1 - n2 * s1;
    ptr[lane + 64] = n2 * c2 + n1 * s2;
}

// ---------------------------------------------------------------------------
// fp32 flash attention (full softmax, no mask). One block = (b, h, 64 q rows).
// 256 threads = 4 waves x 16 q-rows; 4 lanes (a "quad") share one q row,
// each lane owns 32 of the 128 dims (d = quad*4 + 16*i + c).
// K/V tiles of 64 keys staged in LDS. Online softmax in registers.
// ---------------------------------------------------------------------------
__global__ __launch_bounds__(256) void flash_fp32(
    const float* __restrict__ P, float* __restrict__ O)
{
    const int qt  = blockIdx.x;     // 0..31
    const int h   = blockIdx.y;     // 0..15
    const int b   = blockIdx.z;     // 0..1
    const int hkv = h >> 1;         // n_rep = 2
    const int tid  = threadIdx.x;
    const int wave = tid >> 6, lane = tid & 63;
    const int ql   = lane >> 2;             // 0..15
    const int quad = lane & 3;              // 0..3
    const int qrow = qt * 64 + wave * 16 + ql;

    __shared__ float Ks[64][132];
    __shared__ float Vs[64][132];

    const float* qptr = P + ((size_t)(b * SEQ + qrow)) * QKV_LD + h * HD;
    float4 qf[8];
#pragma unroll
    for (int i = 0; i < 8; ++i)
        qf[i] = *(const float4*)(qptr + quad * 4 + i * 16);

    float out[32];
#pragma unroll
    for (int i = 0; i < 32; ++i) out[i] = 0.f;
    float m = -1e30f, l = 0.f;
    const float scale = 0.08838834764831845f;   // 128^-0.5

    for (int kt = 0; kt < SEQ / 64; ++kt) {
        const float* Kb = P + ((size_t)(b * SEQ + kt * 64)) * QKV_LD + HID + hkv * HD;
        const float* Vb = P + ((size_t)(b * SEQ + kt * 64)) * QKV_LD + HID + NKV * HD + hkv * HD;
#pragma unroll
        for (int r = 0; r < 8; ++r) {
            const int idx = tid + r * 256;      // 0..2047
            const int row = idx >> 5;           // 0..63
            const int c4  = (idx & 31) * 4;     // 0..124
            *(float4*)&Ks[row][c4] = *(const float4*)(Kb + (size_t)row * QKV_LD + c4);
            *(float4*)&Vs[row][c4] = *(const float4*)(Vb + (size_t)row * QKV_LD + c4);
        }
        __syncthreads();

        float p[64];
#pragma unroll
        for (int k = 0; k < 64; ++k) {
            float s = 0.f;
#pragma unroll
            for (int i = 0; i < 8; ++i) {
                const float4 kv = *(const float4*)&Ks[k][quad * 4 + i * 16];
                s += qf[i].x * kv.x + qf[i].y * kv.y + qf[i].z * kv.z + qf[i].w * kv.w;
            }
            s += __shfl_xor(s, 1);
            s += __shfl_xor(s, 2);
            p[k] = s * scale;
        }

        float tmax = p[0];
#pragma unroll
        for (int k = 1; k < 64; ++k) tmax = fmaxf(tmax, p[k]);
        const float mn = fmaxf(m, tmax);
        const float alpha = __expf(m - mn);
        float sum = 0.f;
#pragma unroll
        for (int k = 0; k < 64; ++k) { p[k] = __expf(p[k] - mn); sum += p[k]; }
        l = l * alpha + sum;
        m = mn;
#pragma unroll
        for (int i = 0; i < 32; ++i) out[i] *= alpha;

#pragma unroll
        for (int k = 0; k < 64; ++k) {
#pragma unroll
            for (int i = 0; i < 8; ++i) {
                const float4 vv = *(const float4*)&Vs[k][quad * 4 + i * 16];
                out[i * 4 + 0] += p[k] * vv.x;
                out[i * 4 + 1] += p[k] * vv.y;
                out[i * 4 + 2] += p[k] * vv.z;
                out[i * 4 + 3] += p[k] * vv.w;
            }
        }
        __syncthreads();
    }

    const float inv = 1.0f / l;
    float* op = O + ((size_t)(b * SEQ + qrow)) * HID + h * HD;
#pragma unroll
    for (int i = 0; i < 8; ++i) {
        *(float4*)(op + quad * 4 + i * 16) =
            make_float4(out[i * 4 + 0] * inv, out[i * 4 + 1] * inv,
                        out[i * 4 + 2] * inv, out[i * 4 + 3] * inv);
    }
}

// ---------------------------------------------------------------------------
extern "C" void kernel_launch(void* const* d_in, const int* in_sizes, int n_in,
                              void* d_out, int out_size, void* d_ws, size_t ws_size,
                              hipStream_t stream)
{
    (void)in_sizes; (void)n_in; (void)out_size; (void)ws_size;
    const float* hidden = (const float*)d_in[0];
    const float* cosb   = (const float*)d_in[1];
    const float* sinb   = (const float*)d_in[2];
    const float* Wq     = (const float*)d_in[3];
    const float* Wk     = (const float*)d_in[4];
    const float* Wv     = (const float*)d_in[5];
    const float* Wo     = (const float*)d_in[6];
    const float* qw     = (const float*)d_in[7];
    const float* kw     = (const float*)d_in[8];
    float* out = (float*)d_out;

    float* P    = (float*)d_ws;                                    // [4096][4096]
    float* attn = (float*)((char*)d_ws + (size_t)TOK * QKV_LD * 4); // [4096][2048]

    const dim3 blk(256);
    // QKV projections into P: [q | k | v]
    sgemm_bt<<<dim3(16, 32), blk, 0, stream>>>(hidden, Wq, P, HID, QKV_LD, 0);
    sgemm_bt<<<dim3( 8, 32), blk, 0, stream>>>(hidden, Wk, P, HID, QKV_LD, HID);
    sgemm_bt<<<dim3( 8, 32), blk, 0, stream>>>(hidden, Wv, P, HID, QKV_LD, HID + NKV * HD);
    // RMS-norm + RoPE on q,k rows
    norm_rope<<<dim3(6, TOK), blk, 0, stream>>>(P, cosb, sinb, qw, kw);
    // Attention -> attn buffer in [b, s, h*d] layout
    flash_fp32<<<dim3(SEQ / 64, NH, BATCH), blk, 0, stream>>>(P, attn);
    // Output projection
    sgemm_bt<<<dim3(16, 32), blk, 0, stream>>>(attn, Wo, out, HID, HID, 0);
}

// Round 2
// 978.794 us; speedup vs baseline: 4.6038x; 4.6038x over previous
//
#include <hip/hip_runtime.h>
#include <cstdint>

#define SEQ 2048
#define BATCH 2
#define TOK (BATCH * SEQ)      // 4096 tokens
#define HID 2048
#define NH 16
#define NKV 8
#define HD 128
#define QKV_LD 4096            // P buffer row: [q 2048 | k 1024 | v 1024]

using bf16x8 = __attribute__((ext_vector_type(8))) short;
using f32x4  = __attribute__((ext_vector_type(4))) float;
using su4    = __attribute__((ext_vector_type(4))) unsigned short;

#define MFMA(a, b, c) __builtin_amdgcn_mfma_f32_16x16x32_bf16(a, b, c, 0, 0, 0)

__device__ inline unsigned short f2bf(float x) {
    unsigned u = __builtin_bit_cast(unsigned, x);
    unsigned r = u + 0x7FFFu + ((u >> 16) & 1u);
    return (unsigned short)(r >> 16);
}
__device__ inline float bf2f(unsigned short h) {
    unsigned u = ((unsigned)h) << 16;
    return __builtin_bit_cast(float, u);
}
__device__ inline void split2(float x, unsigned short& hi, unsigned short& lo) {
    hi = f2bf(x);
    lo = f2bf(x - bf2f(hi));
}

// ---------------------------------------------------------------------------
// Split-bf16 MFMA GEMM: C[m][coff+n] = sum_k A[m][k] * W[n][k]  (fp32 in/out)
// A: [M x K], W: [N x K], both K-contiguous fp32. Per K-step, tiles are split
// in-register to bf16 hi/lo; 3-term MFMA gives ~fp32 accuracy.
// Tile BM=BN=128, BK=32; 256 threads = 4 waves (2x2), wave tile 64x64.
// ---------------------------------------------------------------------------
#define GLDT 40   // 32 + 8 pad (row = 80 B, 16B-aligned, 2-way-max banks)

__global__ __launch_bounds__(256) void gemm_split(
    const float* __restrict__ A, const float* __restrict__ W,
    float* __restrict__ C, int K, int ldc, int coff)
{
    __shared__ unsigned short Ah[128][GLDT], Al[128][GLDT];
    __shared__ unsigned short Wh[128][GLDT], Wl[128][GLDT];

    const int tid = threadIdx.x;
    const int wv = tid >> 6, ln = tid & 63;
    const int wm = wv >> 1, wn = wv & 1;
    const int lr = ln & 15, lq = ln >> 4;
    const int bn = blockIdx.x, bm = blockIdx.y;

    f32x4 acc[4][4] = {};

    const float* Ab = A + (size_t)(bm * 128) * K;
    const float* Wb = W + (size_t)(bn * 128) * K;

    for (int k0 = 0; k0 < K; k0 += 32) {
#pragma unroll
        for (int r = 0; r < 4; ++r) {
            const int idx = tid + r * 256;
            const int row = idx >> 3, c4 = (idx & 7) * 4;
            unsigned short h0, h1, h2, h3, l0, l1, l2, l3;
            float4 a = *(const float4*)(Ab + (size_t)row * K + k0 + c4);
            split2(a.x, h0, l0); split2(a.y, h1, l1);
            split2(a.z, h2, l2); split2(a.w, h3, l3);
            *(su4*)&Ah[row][c4] = su4{h0, h1, h2, h3};
            *(su4*)&Al[row][c4] = su4{l0, l1, l2, l3};
            float4 w = *(const float4*)(Wb + (size_t)row * K + k0 + c4);
            split2(w.x, h0, l0); split2(w.y, h1, l1);
            split2(w.z, h2, l2); split2(w.w, h3, l3);
            *(su4*)&Wh[row][c4] = su4{h0, h1, h2, h3};
            *(su4*)&Wl[row][c4] = su4{l0, l1, l2, l3};
        }
        __syncthreads();

        bf16x8 ah[4], al_[4], bh[4], bl[4];
#pragma unroll
        for (int i = 0; i < 4; ++i) {
            ah[i]  = *(bf16x8*)&Ah[wm * 64 + i * 16 + lr][lq * 8];
            al_[i] = *(bf16x8*)&Al[wm * 64 + i * 16 + lr][lq * 8];
            bh[i]  = *(bf16x8*)&Wh[wn * 64 + i * 16 + lr][lq * 8];
            bl[i]  = *(bf16x8*)&Wl[wn * 64 + i * 16 + lr][lq * 8];
        }
#pragma unroll
        for (int i = 0; i < 4; ++i)
#pragma unroll
            for (int j = 0; j < 4; ++j) {
                acc[i][j] = MFMA(ah[i], bh[j], acc[i][j]);
                acc[i][j] = MFMA(ah[i], bl[j], acc[i][j]);
                acc[i][j] = MFMA(al_[i], bh[j], acc[i][j]);
            }
        __syncthreads();
    }

    float* Cb = C + (size_t)(bm * 128) * ldc + coff + bn * 128;
#pragma unroll
    for (int i = 0; i < 4; ++i)
#pragma unroll
        for (int j = 0; j < 4; ++j)
#pragma unroll
            for (int r = 0; r < 4; ++r)
                Cb[(size_t)(wm * 64 + i * 16 + lq * 4 + r) * ldc
                   + wn * 64 + j * 16 + lr] = acc[i][j][r];
}

// ---------------------------------------------------------------------------
// Fused RMS-norm (per head, 128 dims) + RoPE for q and k rows of P (fp32).
// ---------------------------------------------------------------------------
__global__ __launch_bounds__(256) void norm_rope(
    float* __restrict__ P, const float* __restrict__ cosb,
    const float* __restrict__ sinb, const float* __restrict__ qw,
    const float* __restrict__ kw)
{
    const int t    = blockIdx.y;
    const int wave = threadIdx.x >> 6;
    const int lane = threadIdx.x & 63;
    const int hid  = blockIdx.x * 4 + wave; // 0..23

    float* ptr;
    const float* w;
    if (hid < NH) { ptr = P + (size_t)t * QKV_LD + hid * HD;              w = qw; }
    else          { ptr = P + (size_t)t * QKV_LD + HID + (hid - NH) * HD; w = kw; }

    float x1 = ptr[lane];
    float x2 = ptr[lane + 64];
    float ss = x1 * x1 + x2 * x2;
#pragma unroll
    for (int off = 1; off < 64; off <<= 1) ss += __shfl_xor(ss, off);
    const float r = rsqrtf(ss * (1.f / 128.f) + 1e-6f);
    const float n1 = x1 * r * w[lane];
    const float n2 = x2 * r * w[lane + 64];

    const float* cp = cosb + (size_t)t * HD;
    const float* sp = sinb + (size_t)t * HD;
    ptr[lane]      = n1 * cp[lane]      - n2 * sp[lane];
    ptr[lane + 64] = n2 * cp[lane + 64] + n1 * sp[lane + 64];
}

// ---------------------------------------------------------------------------
// MFMA flash attention. Block = 256 thr = 4 waves; block tile = 64 q rows
// (16 per wave); K-tiles of 64 keys. Q/K split-bf16 (3-term QK^T), P/V plain
// bf16-hi (softmax averaging suppresses their rounding noise). V staged
// transposed in LDS with XOR swizzle on key-blocks-of-8.
// ---------------------------------------------------------------------------
__global__ __launch_bounds__(256) void flash_mfma(
    const float* __restrict__ P, float* __restrict__ O)
{
    __shared__ unsigned short Kh[64][136], Kl[64][136];  // [key][d], pad 8
    __shared__ unsigned short Vt[128][72];               // [d][key^swz], pad 8
    __shared__ unsigned short Pl[4][16][72];             // per-wave P tile

    const int qt = blockIdx.x, h = blockIdx.y, b = blockIdx.z;
    const int hkv = h >> 1;
    const int tid = threadIdx.x, wv = tid >> 6, ln = tid & 63;
    const int lr = ln & 15, lq = ln >> 4;
    const int qbase = qt * 64 + wv * 16;
    const float scale = 0.08838834764831845f;   // 128^-0.5 (folded into Q)

    // Q fragments (hi/lo), pre-scaled
    bf16x8 qh[4], ql[4];
    {
        const float* qp = P + (size_t)(b * SEQ + qbase + lr) * QKV_LD + h * HD + lq * 8;
#pragma unroll
        for (int kc = 0; kc < 4; ++kc) {
            float v[8];
            float4 x = *(const float4*)(qp + kc * 32);
            float4 y = *(const float4*)(qp + kc * 32 + 4);
            v[0] = x.x; v[1] = x.y; v[2] = x.z; v[3] = x.w;
            v[4] = y.x; v[5] = y.y; v[6] = y.z; v[7] = y.w;
            short th[8], tl[8];
#pragma unroll
            for (int j = 0; j < 8; ++j) {
                unsigned short hh, ll;
                split2(v[j] * scale, hh, ll);
                th[j] = (short)hh; tl[j] = (short)ll;
            }
            qh[kc] = *(bf16x8*)th;
            ql[kc] = *(bf16x8*)tl;
        }
    }

    float m_[4], l_[4];
    f32x4 o_[8] = {};
#pragma unroll
    for (int r = 0; r < 4; ++r) { m_[r] = -1e30f; l_[r] = 0.f; }

    for (int kt = 0; kt < SEQ / 64; ++kt) {
        const float* Kb = P + (size_t)(b * SEQ + kt * 64) * QKV_LD + HID + hkv * HD;
        const float* Vb = Kb + NKV * HD;
#pragma unroll
        for (int r = 0; r < 8; ++r) {
            const int idx = tid + r * 256;
            const int row = idx >> 5, c4 = (idx & 31) * 4;   // row=key, c4=d
            unsigned short h0, h1, h2, h3, l0, l1, l2, l3;
            float4 kv = *(const float4*)(Kb + (size_t)row * QKV_LD + c4);
            split2(kv.x, h0, l0); split2(kv.y, h1, l1);
            split2(kv.z, h2, l2); split2(kv.w, h3, l3);
            *(su4*)&Kh[row][c4] = su4{h0, h1, h2, h3};
            *(su4*)&Kl[row][c4] = su4{l0, l1, l2, l3};
            float4 vv = *(const float4*)(Vb + (size_t)row * QKV_LD + c4);
            float vals[4] = {vv.x, vv.y, vv.z, vv.w};
#pragma unroll
            for (int w = 0; w < 4; ++w) {
                const int d = c4 + w;
                Vt[d][row ^ (((d >> 2) & 7) << 3)] = f2bf(vals[w]);
            }
        }
        __syncthreads();

        // QK^T: S[16 q][64 keys] as 4 n-tiles, split-bf16 3-term
        f32x4 s[4];
#pragma unroll
        for (int nt = 0; nt < 4; ++nt) {
            f32x4 sa = {};
#pragma unroll
            for (int kc = 0; kc < 4; ++kc) {
                bf16x8 kh = *(bf16x8*)&Kh[nt * 16 + lr][kc * 32 + lq * 8];
                bf16x8 kl = *(bf16x8*)&Kl[nt * 16 + lr][kc * 32 + lq * 8];
                sa = MFMA(qh[kc], kh, sa);
                sa = MFMA(qh[kc], kl, sa);
                sa = MFMA(ql[kc], kh, sa);
            }
            s[nt] = sa;
        }

        // online softmax; lane owns q-rows lq*4+r, keys lr+16*nt
        float pm[4];
#pragma unroll
        for (int r = 0; r < 4; ++r) {
            float v = fmaxf(fmaxf(s[0][r], s[1][r]), fmaxf(s[2][r], s[3][r]));
            v = fmaxf(v, __shfl_xor(v, 1));
            v = fmaxf(v, __shfl_xor(v, 2));
            v = fmaxf(v, __shfl_xor(v, 4));
            v = fmaxf(v, __shfl_xor(v, 8));
            pm[r] = v;
        }
        float alpha[4];
#pragma unroll
        for (int r = 0; r < 4; ++r) {
            const float mn = fmaxf(m_[r], pm[r]);
            alpha[r] = __expf(m_[r] - mn);
            m_[r] = mn;
        }
        float rs[4] = {0.f, 0.f, 0.f, 0.f};
#pragma unroll
        for (int nt = 0; nt < 4; ++nt)
#pragma unroll
            for (int r = 0; r < 4; ++r) {
                const float p = __expf(s[nt][r] - m_[r]);
                s[nt][r] = p;
                rs[r] += p;
            }
#pragma unroll
        for (int r = 0; r < 4; ++r) {
            float v = rs[r];
            v += __shfl_xor(v, 1);
            v += __shfl_xor(v, 2);
            v += __shfl_xor(v, 4);
            v += __shfl_xor(v, 8);
            l_[r] = l_[r] * alpha[r] + v;
        }
#pragma unroll
        for (int nt2 = 0; nt2 < 8; ++nt2)
#pragma unroll
            for (int r = 0; r < 4; ++r) o_[nt2][r] *= alpha[r];

        // P -> per-wave LDS (bf16), then re-read as A-fragments
#pragma unroll
        for (int nt = 0; nt < 4; ++nt)
#pragma unroll
            for (int r = 0; r < 4; ++r)
                Pl[wv][lq * 4 + r][nt * 16 + lr] = f2bf(s[nt][r]);
        bf16x8 pa0 = *(bf16x8*)&Pl[wv][lr][lq * 8];
        bf16x8 pa1 = *(bf16x8*)&Pl[wv][lr][32 + lq * 8];

        // PV: O[16 q][128 d] += P(16x64) x V(64x128)
#pragma unroll
        for (int nt2 = 0; nt2 < 8; ++nt2) {
            const int d0 = nt2 * 16 + lr;
            const int g0 = (d0 >> 2) & 7;
            bf16x8 v0 = *(bf16x8*)&Vt[d0][((0 + lq) ^ g0) * 8];
            bf16x8 v1 = *(bf16x8*)&Vt[d0][((4 + lq) ^ g0) * 8];
            o_[nt2] = MFMA(pa0, v0, o_[nt2]);
            o_[nt2] = MFMA(pa1, v1, o_[nt2]);
        }
        __syncthreads();
    }

    float inv[4];
#pragma unroll
    for (int r = 0; r < 4; ++r) inv[r] = 1.0f / l_[r];
    float* op = O + (size_t)(b * SEQ + qbase) * HID + h * HD;
#pragma unroll
    for (int nt2 = 0; nt2 < 8; ++nt2)
#pragma unroll
        for (int r = 0; r < 4; ++r)
            op[(size_t)(lq * 4 + r) * HID + nt2 * 16 + lr] = o_[nt2][r] * inv[r];
}

// ---------------------------------------------------------------------------
extern "C" void kernel_launch(void* const* d_in, const int* in_sizes, int n_in,
                              void* d_out, int out_size, void* d_ws, size_t ws_size,
                              hipStream_t stream)
{
    (void)in_sizes; (void)n_in; (void)out_size; (void)ws_size;
    const float* hidden = (const float*)d_in[0];
    const float* cosb   = (const float*)d_in[1];
    const float* sinb   = (const float*)d_in[2];
    const float* Wq     = (const float*)d_in[3];
    const float* Wk     = (const float*)d_in[4];
    const float* Wv     = (const float*)d_in[5];
    const float* Wo     = (const float*)d_in[6];
    const float* qw     = (const float*)d_in[7];
    const float* kw     = (const float*)d_in[8];
    float* out = (float*)d_out;

    float* P    = (float*)d_ws;                                     // [4096][4096]
    float* attn = (float*)((char*)d_ws + (size_t)TOK * QKV_LD * 4); // [4096][2048]

    const dim3 blk(256);
    gemm_split<<<dim3(16, 32), blk, 0, stream>>>(hidden, Wq, P, HID, QKV_LD, 0);
    gemm_split<<<dim3( 8, 32), blk, 0, stream>>>(hidden, Wk, P, HID, QKV_LD, HID);
    gemm_split<<<dim3( 8, 32), blk, 0, stream>>>(hidden, Wv, P, HID, QKV_LD, HID + NKV * HD);
    norm_rope<<<dim3(6, TOK), blk, 0, stream>>>(P, cosb, sinb, qw, kw);
    flash_mfma<<<dim3(SEQ / 64, NH, BATCH), blk, 0, stream>>>(P, attn);
    gemm_split<<<dim3(16, 32), blk, 0, stream>>>(attn, Wo, out, HID, HID, 0);
}

// Round 3
// 667.599 us; speedup vs baseline: 6.7498x; 1.4661x over previous
//
#include <hip/hip_runtime.h>
#include <cstdint>

#define SEQ 2048
#define BATCH 2
#define TOK 4096
#define HID 2048
#define NH 16
#define NKV 8
#define HD 128
#define QKV_LD 4096

using bf16x8 = __attribute__((ext_vector_type(8))) short;
using f32x4  = __attribute__((ext_vector_type(4))) float;

#define MFMA(a, b, c) __builtin_amdgcn_mfma_f32_16x16x32_bf16(a, b, c, 0, 0, 0)

__device__ inline unsigned short f2bf(float x) {
    unsigned u = __builtin_bit_cast(unsigned, x);
    unsigned r = u + 0x7FFFu + ((u >> 16) & 1u);
    return (unsigned short)(r >> 16);
}
__device__ inline float bf2f(unsigned short h) {
    unsigned u = ((unsigned)h) << 16;
    return __builtin_bit_cast(float, u);
}
__device__ inline void split2(float x, unsigned short& hi, unsigned short& lo) {
    hi = f2bf(x);
    lo = f2bf(x - bf2f(hi));
}
__device__ inline void gload16(const void* g, void* l) {
    __builtin_amdgcn_global_load_lds(
        (const __attribute__((address_space(1))) unsigned*)g,
        (__attribute__((address_space(3))) unsigned*)l, 16, 0, 0);
}

// ---------------------------------------------------------------------------
// split_swz: fp32 [R][2048] -> hi/lo bf16 [R][2048], 16B chunks swizzled
// within 64B segments: pos = (g & ~3) | ((g&3) ^ (row&3)).
// One block per row; lane = 16B output chunk (8 elems).
// ---------------------------------------------------------------------------
__global__ __launch_bounds__(256) void split_swz(
    const float* __restrict__ X, unsigned short* __restrict__ Xh,
    unsigned short* __restrict__ Xl)
{
    const int row = blockIdx.x;
    const int g   = threadIdx.x;            // chunk 0..255
    const float* src = X + (size_t)row * HID + g * 8;
    float v[8];
    float4 a = *(const float4*)src;
    float4 b = *(const float4*)(src + 4);
    v[0]=a.x; v[1]=a.y; v[2]=a.z; v[3]=a.w; v[4]=b.x; v[5]=b.y; v[6]=b.z; v[7]=b.w;
    bf16x8 vh, vl;
#pragma unroll
    for (int i = 0; i < 8; ++i) {
        unsigned short h, l;
        split2(v[i], h, l);
        vh[i] = (short)h; vl[i] = (short)l;
    }
    const int pos = (g & ~3) | ((g & 3) ^ (row & 3));
    *(bf16x8*)((char*)Xh + (size_t)row * 4096 + pos * 16) = vh;
    *(bf16x8*)((char*)Xl + (size_t)row * 4096 + pos * 16) = vl;
}

// ---------------------------------------------------------------------------
// gemm3: C[m][coff+n] = sum_k A[m][k]*W[n][k], 3-term split-bf16 MFMA.
// Operands pre-split+pre-swizzled bf16 (ld 2048). Tile 128x128, BK=32.
// Staging via global_load_lds (linear LDS, swizzle baked into source).
// ---------------------------------------------------------------------------
__global__ __launch_bounds__(256) void gemm3(
    const unsigned short* __restrict__ Ah_g, const unsigned short* __restrict__ Al_g,
    const unsigned short* __restrict__ Bh_g, const unsigned short* __restrict__ Bl_g,
    float* __restrict__ C, int ldc, int coff)
{
    __shared__ char lds[4][8192];   // Ah, Al, Bh, Bl tiles [128 rows][64 B]

    const int tid = threadIdx.x;
    const int wv = tid >> 6, ln = tid & 63;
    const int wm = wv >> 1, wn = wv & 1;
    const int lr = ln & 15, lq = ln >> 4;
    const int bn = blockIdx.x, bm = blockIdx.y;

    f32x4 acc[4][4] = {};
    const size_t arow0 = (size_t)bm * 128;
    const size_t brow0 = (size_t)bn * 128;

    for (int k0 = 0; k0 < HID; k0 += 32) {
#pragma unroll
        for (int r = 0; r < 2; ++r) {
            const int idx = r * 256 + tid;
            const int row = idx >> 2;          // 0..127
            const int ch  = tid & 3;
            const size_t ka = ((arow0 + row) * (size_t)HID + k0) * 2 + ch * 16;
            const size_t kb = ((brow0 + row) * (size_t)HID + k0) * 2 + ch * 16;
            const int dst = (r * 256 + (tid >> 6) * 64) * 16;   // wave-uniform
            gload16((const char*)Ah_g + ka, &lds[0][dst]);
            gload16((const char*)Al_g + ka, &lds[1][dst]);
            gload16((const char*)Bh_g + kb, &lds[2][dst]);
            gload16((const char*)Bl_g + kb, &lds[3][dst]);
        }
        __syncthreads();

        bf16x8 ah[4], al[4], bh[4], bl[4];
#pragma unroll
        for (int i = 0; i < 4; ++i) {
            const int ra = wm * 64 + i * 16 + lr;
            const int xa = (lq ^ (ra & 3)) << 4;
            ah[i] = *(bf16x8*)&lds[0][ra * 64 + xa];
            al[i] = *(bf16x8*)&lds[1][ra * 64 + xa];
            const int rb = wn * 64 + i * 16 + lr;
            const int xb = (lq ^ (rb & 3)) << 4;
            bh[i] = *(bf16x8*)&lds[2][rb * 64 + xb];
            bl[i] = *(bf16x8*)&lds[3][rb * 64 + xb];
        }
#pragma unroll
        for (int i = 0; i < 4; ++i)
#pragma unroll
            for (int j = 0; j < 4; ++j) {
                acc[i][j] = MFMA(ah[i], bh[j], acc[i][j]);
                acc[i][j] = MFMA(ah[i], bl[j], acc[i][j]);
                acc[i][j] = MFMA(al[i], bh[j], acc[i][j]);
            }
        __syncthreads();
    }

    float* Cb = C + arow0 * ldc + coff + bn * 128;
#pragma unroll
    for (int i = 0; i < 4; ++i)
#pragma unroll
        for (int j = 0; j < 4; ++j)
#pragma unroll
            for (int r = 0; r < 4; ++r)
                Cb[(size_t)(wm * 64 + i * 16 + lq * 4 + r) * ldc
                   + wn * 64 + j * 16 + lr] = acc[i][j][r];
}

// ---------------------------------------------------------------------------
// norm_rope: q heads -> in-place fp32; k heads -> RMS+RoPE then split-bf16,
// written pre-swizzled to KhG/KlG [b][kv][s][128] (16 chunks/row, ^= s&7).
// ---------------------------------------------------------------------------
__global__ __launch_bounds__(256) void norm_rope(
    float* __restrict__ P, const float* __restrict__ cosb,
    const float* __restrict__ sinb, const float* __restrict__ qw,
    const float* __restrict__ kw, unsigned short* __restrict__ KhG,
    unsigned short* __restrict__ KlG)
{
    const int t    = blockIdx.y;
    const int wave = threadIdx.x >> 6;
    const int lane = threadIdx.x & 63;
    const int hid  = blockIdx.x * 4 + wave; // 0..23

    float* ptr;
    const float* w;
    if (hid < NH) { ptr = P + (size_t)t * QKV_LD + hid * HD;              w = qw; }
    else          { ptr = P + (size_t)t * QKV_LD + HID + (hid - NH) * HD; w = kw; }

    float x1 = ptr[lane];
    float x2 = ptr[lane + 64];
    float ss = x1 * x1 + x2 * x2;
#pragma unroll
    for (int off = 1; off < 64; off <<= 1) ss += __shfl_xor(ss, off);
    const float r = rsqrtf(ss * (1.f / 128.f) + 1e-6f);
    const float n1 = x1 * r * w[lane];
    const float n2 = x2 * r * w[lane + 64];

    const float* cp = cosb + (size_t)t * HD;
    const float* sp = sinb + (size_t)t * HD;
    const float o1 = n1 * cp[lane]      - n2 * sp[lane];
    const float o2 = n2 * cp[lane + 64] + n1 * sp[lane + 64];

    if (hid < NH) {
        ptr[lane]      = o1;
        ptr[lane + 64] = o2;
    } else {
        const int b = t / SEQ, s = t % SEQ, kv = hid - NH;
        const size_t base = ((size_t)(b * NKV + kv) * SEQ + s) * 256;  // bytes
        const int s7 = s & 7;
        unsigned short h1, l1, h2, l2;
        split2(o1, h1, l1); split2(o2, h2, l2);
        const int d1 = lane, d2 = lane + 64;
        char* ph = (char*)KhG + base;
        char* pl = (char*)KlG + base;
        *(unsigned short*)(ph + (((d1 >> 3) ^ s7) << 4) + ((d1 & 7) << 1)) = h1;
        *(unsigned short*)(ph + (((d2 >> 3) ^ s7) << 4) + ((d2 & 7) << 1)) = h2;
        *(unsigned short*)(pl + (((d1 >> 3) ^ s7) << 4) + ((d1 & 7) << 1)) = l1;
        *(unsigned short*)(pl + (((d2 >> 3) ^ s7) << 4) + ((d2 & 7) << 1)) = l2;
    }
}

// ---------------------------------------------------------------------------
// conv_v: V fp32 rows of P -> transposed bf16 VtG [b][kv][d=128][s=2048],
// pre-swizzled (8 chunks per 64-key group, ^= d&7). Block = 64 tokens x 1 kv.
// ---------------------------------------------------------------------------
__global__ __launch_bounds__(256) void conv_v(
    const float* __restrict__ P, unsigned short* __restrict__ VtG)
{
    __shared__ float Ts[64][133];
    const int kb = blockIdx.x;      // 64-token block over TOK
    const int kv = blockIdx.y;
    const int tid = threadIdx.x;

#pragma unroll
    for (int r = 0; r < 8; ++r) {
        const int idx = tid + r * 256;
        const int row = idx >> 5, c4 = (idx & 31) * 4;
        float4 v = *(const float4*)(P + (size_t)(kb * 64 + row) * QKV_LD
                                    + HID + NKV * HD + kv * HD + c4);
        Ts[row][c4 + 0] = v.x; Ts[row][c4 + 1] = v.y;
        Ts[row][c4 + 2] = v.z; Ts[row][c4 + 3] = v.w;
    }
    __syncthreads();

    const int b  = (kb * 64) / SEQ;
    const int s0 = (kb * 64) % SEQ;
#pragma unroll
    for (int w = 0; w < 4; ++w) {
        const int idx = tid + w * 256;      // 0..1023
        const int d = idx >> 3, c = idx & 7;
        bf16x8 pk;
#pragma unroll
        for (int kk = 0; kk < 8; ++kk) pk[kk] = (short)f2bf(Ts[c * 8 + kk][d]);
        char* dst = (char*)VtG + ((size_t)(b * NKV + kv) * 128 + d) * 4096
                    + (s0 / 8 + (c ^ (d & 7))) * 16;
        *(bf16x8*)dst = pk;
    }
}

// ---------------------------------------------------------------------------
// flash2: MFMA flash attention with pre-split K (hi/lo) and pre-transposed V,
// all staged via global_load_lds into linear LDS; XOR-swizzled reads.
// Block = 4 waves x 16 q rows; K-tiles of 64 keys.
// ---------------------------------------------------------------------------
__global__ __launch_bounds__(256) void flash2(
    const float* __restrict__ P, const unsigned short* __restrict__ KhG,
    const unsigned short* __restrict__ KlG, const unsigned short* __restrict__ VtG,
    float* __restrict__ O)
{
    __shared__ char KhL[16384], KlL[16384], VtL[16384];
    __shared__ unsigned short Pl[4][16][72];

    const int qt = blockIdx.x, h = blockIdx.y, b = blockIdx.z;
    const int hkv = h >> 1;
    const int tid = threadIdx.x, wv = tid >> 6, ln = tid & 63;
    const int lr = ln & 15, lq = ln >> 4;
    const int qbase = qt * 64 + wv * 16;
    const float scale = 0.08838834764831845f;   // 128^-0.5 folded into Q

    bf16x8 qh[4], ql[4];
    {
        const float* qp = P + (size_t)(b * SEQ + qbase + lr) * QKV_LD + h * HD + lq * 8;
#pragma unroll
        for (int kc = 0; kc < 4; ++kc) {
            float v[8];
            float4 x = *(const float4*)(qp + kc * 32);
            float4 y = *(const float4*)(qp + kc * 32 + 4);
            v[0]=x.x; v[1]=x.y; v[2]=x.z; v[3]=x.w; v[4]=y.x; v[5]=y.y; v[6]=y.z; v[7]=y.w;
#pragma unroll
            for (int j = 0; j < 8; ++j) {
                unsigned short hh, ll;
                split2(v[j] * scale, hh, ll);
                qh[kc][j] = (short)hh; ql[kc][j] = (short)ll;
            }
        }
    }

    float m_[4], l_[4];
    f32x4 o_[8] = {};
#pragma unroll
    for (int r = 0; r < 4; ++r) { m_[r] = -1e30f; l_[r] = 0.f; }

    const size_t krow = (size_t)(b * NKV + hkv) * SEQ;   // key-row base (256B rows)
    const size_t vrow = (size_t)(b * NKV + hkv) * 128;   // Vt d-row base (4096B rows)

    for (int kt = 0; kt < SEQ / 64; ++kt) {
#pragma unroll
        for (int r = 0; r < 4; ++r) {
            const int idx = tid + r * 256;
            const int dst = (r * 256 + (tid >> 6) * 64) * 16;
            gload16((const char*)KhG + (krow + kt * 64 + (idx >> 4)) * 256 + (idx & 15) * 16,
                    KhL + dst);
            gload16((const char*)KlG + (krow + kt * 64 + (idx >> 4)) * 256 + (idx & 15) * 16,
                    KlL + dst);
            gload16((const char*)VtG + (vrow + (idx >> 3)) * 4096 + kt * 128 + (idx & 7) * 16,
                    VtL + dst);
        }
        __syncthreads();

        // QK^T: S[16 q][64 keys], 3-term split
        f32x4 s[4];
#pragma unroll
        for (int nt = 0; nt < 4; ++nt) {
            const int key = nt * 16 + lr;
            f32x4 sa = {};
#pragma unroll
            for (int kc = 0; kc < 4; ++kc) {
                const int ch = ((kc * 4 + lq) ^ (lr & 7)) << 4;
                bf16x8 kh = *(bf16x8*)(KhL + key * 256 + ch);
                bf16x8 kl = *(bf16x8*)(KlL + key * 256 + ch);
                sa = MFMA(qh[kc], kh, sa);
                sa = MFMA(qh[kc], kl, sa);
                sa = MFMA(ql[kc], kh, sa);
            }
            s[nt] = sa;
        }

        // online softmax
        float pm[4];
#pragma unroll
        for (int r = 0; r < 4; ++r) {
            float v = fmaxf(fmaxf(s[0][r], s[1][r]), fmaxf(s[2][r], s[3][r]));
            v = fmaxf(v, __shfl_xor(v, 1));
            v = fmaxf(v, __shfl_xor(v, 2));
            v = fmaxf(v, __shfl_xor(v, 4));
            v = fmaxf(v, __shfl_xor(v, 8));
            pm[r] = v;
        }
        float alpha[4];
#pragma unroll
        for (int r = 0; r < 4; ++r) {
            const float mn = fmaxf(m_[r], pm[r]);
            alpha[r] = __expf(m_[r] - mn);
            m_[r] = mn;
        }
        float rs[4] = {0.f, 0.f, 0.f, 0.f};
#pragma unroll
        for (int nt = 0; nt < 4; ++nt)
#pragma unroll
            for (int r = 0; r < 4; ++r) {
                const float p = __expf(s[nt][r] - m_[r]);
                s[nt][r] = p;
                rs[r] += p;
            }
#pragma unroll
        for (int r = 0; r < 4; ++r) {
            float v = rs[r];
            v += __shfl_xor(v, 1);
            v += __shfl_xor(v, 2);
            v += __shfl_xor(v, 4);
            v += __shfl_xor(v, 8);
            l_[r] = l_[r] * alpha[r] + v;
        }
#pragma unroll
        for (int nt2 = 0; nt2 < 8; ++nt2)
#pragma unroll
            for (int r = 0; r < 4; ++r) o_[nt2][r] *= alpha[r];

        // P -> bf16 via per-wave LDS roundtrip
#pragma unroll
        for (int nt = 0; nt < 4; ++nt)
#pragma unroll
            for (int r = 0; r < 4; ++r)
                Pl[wv][lq * 4 + r][nt * 16 + lr] = f2bf(s[nt][r]);
        bf16x8 pa0 = *(bf16x8*)&Pl[wv][lr][lq * 8];
        bf16x8 pa1 = *(bf16x8*)&Pl[wv][lr][32 + lq * 8];

        // PV
#pragma unroll
        for (int nt2 = 0; nt2 < 8; ++nt2) {
            const int d0 = nt2 * 16 + lr;
            bf16x8 v0 = *(bf16x8*)(VtL + d0 * 128 + ((lq ^ (lr & 7)) << 4));
            bf16x8 v1 = *(bf16x8*)(VtL + d0 * 128 + (((4 + lq) ^ (lr & 7)) << 4));
            o_[nt2] = MFMA(pa0, v0, o_[nt2]);
            o_[nt2] = MFMA(pa1, v1, o_[nt2]);
        }
        __syncthreads();
    }

    float inv[4];
#pragma unroll
    for (int r = 0; r < 4; ++r) inv[r] = 1.0f / l_[r];
    float* op = O + (size_t)(b * SEQ + qbase) * HID + h * HD;
#pragma unroll
    for (int nt2 = 0; nt2 < 8; ++nt2)
#pragma unroll
        for (int r = 0; r < 4; ++r)
            op[(size_t)(lq * 4 + r) * HID + nt2 * 16 + lr] = o_[nt2][r] * inv[r];
}

// ---------------------------------------------------------------------------
extern "C" void kernel_launch(void* const* d_in, const int* in_sizes, int n_in,
                              void* d_out, int out_size, void* d_ws, size_t ws_size,
                              hipStream_t stream)
{
    (void)in_sizes; (void)n_in; (void)out_size; (void)ws_size;
    const float* hidden = (const float*)d_in[0];
    const float* cosb   = (const float*)d_in[1];
    const float* sinb   = (const float*)d_in[2];
    const float* Wq     = (const float*)d_in[3];
    const float* Wk     = (const float*)d_in[4];
    const float* Wv     = (const float*)d_in[5];
    const float* Wo     = (const float*)d_in[6];
    const float* qw     = (const float*)d_in[7];
    const float* kw     = (const float*)d_in[8];
    float* out = (float*)d_out;

    char* ws = (char*)d_ws;
    const size_t MB = 1ull << 20;
    float*          P    = (float*)(ws);                       // 64 MB
    float*          attn = (float*)(ws + 64  * MB);            // 32 MB
    unsigned short* Ah   = (unsigned short*)(ws + 96  * MB);   // 16 MB (hidden, then attn)
    unsigned short* Al   = (unsigned short*)(ws + 112 * MB);   // 16 MB
    unsigned short* Wqh  = (unsigned short*)(ws + 128 * MB);   // 8 MB (then Wo hi)
    unsigned short* Wql  = (unsigned short*)(ws + 136 * MB);   // 8 MB (then Wo lo)
    unsigned short* Wkh  = (unsigned short*)(ws + 144 * MB);   // 4 MB
    unsigned short* Wkl  = (unsigned short*)(ws + 148 * MB);   // 4 MB
    unsigned short* Wvh  = (unsigned short*)(ws + 152 * MB);   // 4 MB
    unsigned short* Wvl  = (unsigned short*)(ws + 156 * MB);   // 4 MB
    unsigned short* KhG  = (unsigned short*)(ws + 160 * MB);   // 8 MB
    unsigned short* KlG  = (unsigned short*)(ws + 168 * MB);   // 8 MB
    unsigned short* VtG  = (unsigned short*)(ws + 176 * MB);   // 8 MB -> ends 184 MB

    const dim3 blk(256);
    split_swz<<<TOK,  blk, 0, stream>>>(hidden, Ah, Al);
    split_swz<<<2048, blk, 0, stream>>>(Wq, Wqh, Wql);
    split_swz<<<1024, blk, 0, stream>>>(Wk, Wkh, Wkl);
    split_swz<<<1024, blk, 0, stream>>>(Wv, Wvh, Wvl);

    gemm3<<<dim3(16, 32), blk, 0, stream>>>(Ah, Al, Wqh, Wql, P, QKV_LD, 0);
    gemm3<<<dim3( 8, 32), blk, 0, stream>>>(Ah, Al, Wkh, Wkl, P, QKV_LD, HID);
    gemm3<<<dim3( 8, 32), blk, 0, stream>>>(Ah, Al, Wvh, Wvl, P, QKV_LD, HID + NKV * HD);

    norm_rope<<<dim3(6, TOK), blk, 0, stream>>>(P, cosb, sinb, qw, kw, KhG, KlG);
    conv_v<<<dim3(TOK / 64, NKV), blk, 0, stream>>>(P, VtG);

    flash2<<<dim3(SEQ / 64, NH, BATCH), blk, 0, stream>>>(P, KhG, KlG, VtG, attn);

    split_swz<<<TOK,  blk, 0, stream>>>(attn, Ah, Al);          // reuse region
    split_swz<<<2048, blk, 0, stream>>>(Wo, Wqh, Wql);          // reuse region
    gemm3<<<dim3(16, 32), blk, 0, stream>>>(Ah, Al, Wqh, Wql, out, HID, 0);
}

// Round 4
// 384.067 us; speedup vs baseline: 11.7328x; 1.7382x over previous
//
#include <hip/hip_runtime.h>
#include <cstdint>

#define SEQ 2048
#define BATCH 2
#define TOK 4096
#define HID 2048
#define NH 16
#define NKV 8
#define HD 128
#define QKV_LD 4096

using f16x8 = __attribute__((ext_vector_type(8))) _Float16;
using f32x4 = __attribute__((ext_vector_type(4))) float;

#define MFMA(a, b, c) __builtin_amdgcn_mfma_f32_16x16x32_f16(a, b, c, 0, 0, 0)

__device__ inline void gload16(const void* g, void* l) {
    __builtin_amdgcn_global_load_lds(
        (const __attribute__((address_space(1))) unsigned*)g,
        (__attribute__((address_space(3))) unsigned*)l, 16, 0, 0);
}

// ---------------------------------------------------------------------------
// conv_h: fp32 [R][2048] -> fp16 [R][2048], 16B chunks swizzled within 64B
// groups: pos = (g & ~3) | ((g&3) ^ (row&3)). One block per row.
// ---------------------------------------------------------------------------
__global__ __launch_bounds__(256) void conv_h(
    const float* __restrict__ X, _Float16* __restrict__ Y)
{
    const int row = blockIdx.x;
    const int g   = threadIdx.x;            // chunk 0..255
    const float* src = X + (size_t)row * HID + g * 8;
    float4 a = *(const float4*)src;
    float4 b = *(const float4*)(src + 4);
    f16x8 v;
    v[0] = (_Float16)a.x; v[1] = (_Float16)a.y;
    v[2] = (_Float16)a.z; v[3] = (_Float16)a.w;
    v[4] = (_Float16)b.x; v[5] = (_Float16)b.y;
    v[6] = (_Float16)b.z; v[7] = (_Float16)b.w;
    const int pos = (g & ~3) | ((g & 3) ^ (row & 3));
    *(f16x8*)((char*)Y + (size_t)row * 4096 + pos * 16) = v;
}

// ---------------------------------------------------------------------------
// gemm_f16: C[m][coff+n] = sum_k A[m][k]*B[n][k], fp16 MFMA, fp32 accum/out.
// A,B pre-converted + pre-swizzled fp16 (ld 2048). Tile 128x128, BK=32,
// 256 thr = 4 waves (2x2). Staging via global_load_lds (linear LDS).
// ---------------------------------------------------------------------------
__global__ __launch_bounds__(256) void gemm_f16(
    const _Float16* __restrict__ Ag, const _Float16* __restrict__ Bg,
    float* __restrict__ C, int ldc, int coff)
{
    __shared__ char ldsA[8192], ldsB[8192];   // [128 rows][64 B]

    const int tid = threadIdx.x;
    const int wv = tid >> 6, ln = tid & 63;
    const int wm = wv >> 1, wn = wv & 1;
    const int lr = ln & 15, lq = ln >> 4;
    const int bn = blockIdx.x, bm = blockIdx.y;

    f32x4 acc[4][4] = {};
    const size_t arow0 = (size_t)bm * 128;
    const size_t brow0 = (size_t)bn * 128;

    for (int k0 = 0; k0 < HID; k0 += 32) {
#pragma unroll
        for (int r = 0; r < 2; ++r) {
            const int idx = r * 256 + tid;
            const int row = idx >> 2;          // 0..127
            const int ch  = tid & 3;
            const size_t ga = ((arow0 + row) * (size_t)HID + k0) * 2 + ch * 16;
            const size_t gb = ((brow0 + row) * (size_t)HID + k0) * 2 + ch * 16;
            const int dst = (r * 256 + wv * 64) * 16;   // wave-uniform base
            gload16((const char*)Ag + ga, ldsA + dst);
            gload16((const char*)Bg + gb, ldsB + dst);
        }
        __syncthreads();

        f16x8 a[4], b[4];
#pragma unroll
        for (int i = 0; i < 4; ++i) {
            const int ra = wm * 64 + i * 16 + lr;
            a[i] = *(f16x8*)&ldsA[ra * 64 + ((lq ^ (ra & 3)) << 4)];
            const int rb = wn * 64 + i * 16 + lr;
            b[i] = *(f16x8*)&ldsB[rb * 64 + ((lq ^ (rb & 3)) << 4)];
        }
#pragma unroll
        for (int i = 0; i < 4; ++i)
#pragma unroll
            for (int j = 0; j < 4; ++j)
                acc[i][j] = MFMA(a[i], b[j], acc[i][j]);
        __syncthreads();
    }

    float* Cb = C + arow0 * ldc + coff + bn * 128;
#pragma unroll
    for (int i = 0; i < 4; ++i)
#pragma unroll
        for (int j = 0; j < 4; ++j)
#pragma unroll
            for (int r = 0; r < 4; ++r)
                Cb[(size_t)(wm * 64 + i * 16 + lq * 4 + r) * ldc
                   + wn * 64 + j * 16 + lr] = acc[i][j][r];
}

// ---------------------------------------------------------------------------
// norm_rope: q heads -> in-place fp32 in P; k heads -> RMS+RoPE then fp16,
// written pre-swizzled to KhG [b][kv][s][128] (16 chunks/row, chunk ^= s&7).
// ---------------------------------------------------------------------------
__global__ __launch_bounds__(256) void norm_rope(
    float* __restrict__ P, const float* __restrict__ cosb,
    const float* __restrict__ sinb, const float* __restrict__ qw,
    const float* __restrict__ kw, _Float16* __restrict__ KhG)
{
    const int t    = blockIdx.y;
    const int wave = threadIdx.x >> 6;
    const int lane = threadIdx.x & 63;
    const int hid  = blockIdx.x * 4 + wave; // 0..23

    float* ptr;
    const float* w;
    if (hid < NH) { ptr = P + (size_t)t * QKV_LD + hid * HD;              w = qw; }
    else          { ptr = P + (size_t)t * QKV_LD + HID + (hid - NH) * HD; w = kw; }

    float x1 = ptr[lane];
    float x2 = ptr[lane + 64];
    float ss = x1 * x1 + x2 * x2;
#pragma unroll
    for (int off = 1; off < 64; off <<= 1) ss += __shfl_xor(ss, off);
    const float r = rsqrtf(ss * (1.f / 128.f) + 1e-6f);
    const float n1 = x1 * r * w[lane];
    const float n2 = x2 * r * w[lane + 64];

    const float* cp = cosb + (size_t)t * HD;
    const float* sp = sinb + (size_t)t * HD;
    const float o1 = n1 * cp[lane]      - n2 * sp[lane];
    const float o2 = n2 * cp[lane + 64] + n1 * sp[lane + 64];

    if (hid < NH) {
        ptr[lane]      = o1;
        ptr[lane + 64] = o2;
    } else {
        const int b = t / SEQ, s = t % SEQ, kv = hid - NH;
        char* ph = (char*)KhG + ((size_t)(b * NKV + kv) * SEQ + s) * 256;
        const int s7 = s & 7;
        const int d1 = lane, d2 = lane + 64;
        *(_Float16*)(ph + (((d1 >> 3) ^ s7) << 4) + ((d1 & 7) << 1)) = (_Float16)o1;
        *(_Float16*)(ph + (((d2 >> 3) ^ s7) << 4) + ((d2 & 7) << 1)) = (_Float16)o2;
    }
}

// ---------------------------------------------------------------------------
// conv_v: V fp32 rows of P -> transposed fp16 VtG [b][kv][d=128][s=2048],
// pre-swizzled (8 chunks per 64-key group, chunk ^= d&7).
// ---------------------------------------------------------------------------
__global__ __launch_bounds__(256) void conv_v(
    const float* __restrict__ P, _Float16* __restrict__ VtG)
{
    __shared__ float Ts[64][133];
    const int kb = blockIdx.x;      // 64-token block over TOK
    const int kv = blockIdx.y;
    const int tid = threadIdx.x;

#pragma unroll
    for (int r = 0; r < 8; ++r) {
        const int idx = tid + r * 256;
        const int row = idx >> 5, c4 = (idx & 31) * 4;
        float4 v = *(const float4*)(P + (size_t)(kb * 64 + row) * QKV_LD
                                    + HID + NKV * HD + kv * HD + c4);
        Ts[row][c4 + 0] = v.x; Ts[row][c4 + 1] = v.y;
        Ts[row][c4 + 2] = v.z; Ts[row][c4 + 3] = v.w;
    }
    __syncthreads();

    const int b  = (kb * 64) / SEQ;
    const int s0 = (kb * 64) % SEQ;
#pragma unroll
    for (int w = 0; w < 4; ++w) {
        const int idx = tid + w * 256;      // 0..1023
        const int d = idx >> 3, c = idx & 7;
        f16x8 pk;
#pragma unroll
        for (int kk = 0; kk < 8; ++kk) pk[kk] = (_Float16)Ts[c * 8 + kk][d];
        char* dst = (char*)VtG + ((size_t)(b * NKV + kv) * 128 + d) * 4096
                    + ((s0 >> 3) + (c ^ (d & 7))) * 16;
        *(f16x8*)dst = pk;
    }
}

// ---------------------------------------------------------------------------
// flash_f16: MFMA flash attention, fp16 operands / fp32 softmax+accum.
// Block = 4 waves x 16 q rows; K-tiles of 64 keys. K/V staged via
// global_load_lds (linear LDS, swizzle pre-baked in global layout).
// Output written as fp16 in the GEMM-ready swizzled layout.
// ---------------------------------------------------------------------------
__global__ __launch_bounds__(256) void flash_f16(
    const float* __restrict__ P, const _Float16* __restrict__ KhG,
    const _Float16* __restrict__ VtG, _Float16* __restrict__ OH)
{
    __shared__ char KhL[16384], VtL[16384];
    __shared__ _Float16 Pl[4][16][72];

    const int qt = blockIdx.x, h = blockIdx.y, b = blockIdx.z;
    const int hkv = h >> 1;
    const int tid = threadIdx.x, wv = tid >> 6, ln = tid & 63;
    const int lr = ln & 15, lq = ln >> 4;
    const int qbase = qt * 64 + wv * 16;
    const float scale = 0.08838834764831845f;   // 128^-0.5 folded into Q

    f16x8 qh[4];
    {
        const float* qp = P + (size_t)(b * SEQ + qbase + lr) * QKV_LD + h * HD + lq * 8;
#pragma unroll
        for (int kc = 0; kc < 4; ++kc) {
            float4 x = *(const float4*)(qp + kc * 32);
            float4 y = *(const float4*)(qp + kc * 32 + 4);
            qh[kc][0] = (_Float16)(x.x * scale); qh[kc][1] = (_Float16)(x.y * scale);
            qh[kc][2] = (_Float16)(x.z * scale); qh[kc][3] = (_Float16)(x.w * scale);
            qh[kc][4] = (_Float16)(y.x * scale); qh[kc][5] = (_Float16)(y.y * scale);
            qh[kc][6] = (_Float16)(y.z * scale); qh[kc][7] = (_Float16)(y.w * scale);
        }
    }

    float m_[4], l_[4];
    f32x4 o_[8] = {};
#pragma unroll
    for (int r = 0; r < 4; ++r) { m_[r] = -1e30f; l_[r] = 0.f; }

    const size_t krow = (size_t)(b * NKV + hkv) * SEQ;   // 256B rows
    const size_t vrow = (size_t)(b * NKV + hkv) * 128;   // 4096B rows

    for (int kt = 0; kt < SEQ / 64; ++kt) {
#pragma unroll
        for (int r = 0; r < 4; ++r) {
            const int idx = tid + r * 256;
            const int dst = (r * 256 + wv * 64) * 16;
            gload16((const char*)KhG + (krow + kt * 64 + (idx >> 4)) * 256 + (idx & 15) * 16,
                    KhL + dst);
            gload16((const char*)VtG + (vrow + (idx >> 3)) * 4096 + kt * 128 + (idx & 7) * 16,
                    VtL + dst);
        }
        __syncthreads();

        // QK^T: S[16 q][64 keys]
        f32x4 s[4];
#pragma unroll
        for (int nt = 0; nt < 4; ++nt) {
            const int key = nt * 16 + lr;
            f32x4 sa = {};
#pragma unroll
            for (int kc = 0; kc < 4; ++kc) {
                f16x8 kh = *(f16x8*)(KhL + key * 256 + ((((kc * 4 + lq) ^ (lr & 7))) << 4));
                sa = MFMA(qh[kc], kh, sa);
            }
            s[nt] = sa;
        }

        // online softmax
        float pm[4];
#pragma unroll
        for (int r = 0; r < 4; ++r) {
            float v = fmaxf(fmaxf(s[0][r], s[1][r]), fmaxf(s[2][r], s[3][r]));
            v = fmaxf(v, __shfl_xor(v, 1));
            v = fmaxf(v, __shfl_xor(v, 2));
            v = fmaxf(v, __shfl_xor(v, 4));
            v = fmaxf(v, __shfl_xor(v, 8));
            pm[r] = v;
        }
        float alpha[4];
#pragma unroll
        for (int r = 0; r < 4; ++r) {
            const float mn = fmaxf(m_[r], pm[r]);
            alpha[r] = __expf(m_[r] - mn);
            m_[r] = mn;
        }
        float rs[4] = {0.f, 0.f, 0.f, 0.f};
#pragma unroll
        for (int nt = 0; nt < 4; ++nt)
#pragma unroll
            for (int r = 0; r < 4; ++r) {
                const float p = __expf(s[nt][r] - m_[r]);
                s[nt][r] = p;
                rs[r] += p;
            }
#pragma unroll
        for (int r = 0; r < 4; ++r) {
            float v = rs[r];
            v += __shfl_xor(v, 1);
            v += __shfl_xor(v, 2);
            v += __shfl_xor(v, 4);
            v += __shfl_xor(v, 8);
            l_[r] = l_[r] * alpha[r] + v;
        }
#pragma unroll
        for (int nt2 = 0; nt2 < 8; ++nt2)
#pragma unroll
            for (int r = 0; r < 4; ++r) o_[nt2][r] *= alpha[r];

        // P -> fp16 via per-wave LDS roundtrip
#pragma unroll
        for (int nt = 0; nt < 4; ++nt)
#pragma unroll
            for (int r = 0; r < 4; ++r)
                Pl[wv][lq * 4 + r][nt * 16 + lr] = (_Float16)s[nt][r];
        f16x8 pa0 = *(f16x8*)&Pl[wv][lr][lq * 8];
        f16x8 pa1 = *(f16x8*)&Pl[wv][lr][32 + lq * 8];

        // PV
#pragma unroll
        for (int nt2 = 0; nt2 < 8; ++nt2) {
            const int d0 = nt2 * 16 + lr;
            f16x8 v0 = *(f16x8*)(VtL + d0 * 128 + ((lq ^ (lr & 7)) << 4));
            f16x8 v1 = *(f16x8*)(VtL + d0 * 128 + (((4 + lq) ^ (lr & 7)) << 4));
            o_[nt2] = MFMA(pa0, v0, o_[nt2]);
            o_[nt2] = MFMA(pa1, v1, o_[nt2]);
        }
        __syncthreads();
    }

    float inv[4];
#pragma unroll
    for (int r = 0; r < 4; ++r) inv[r] = 1.0f / l_[r];
    // write fp16, pre-swizzled for gemm_f16 (chunk ^= row&3 within 64B groups)
#pragma unroll
    for (int r = 0; r < 4; ++r) {
        const int R = b * SEQ + qbase + lq * 4 + r;
        char* rowp = (char*)OH + (size_t)R * 4096;
#pragma unroll
        for (int nt2 = 0; nt2 < 8; ++nt2) {
            const int d = h * HD + nt2 * 16 + lr;
            const int g = d >> 3;
            const int pos = (g & ~3) | ((g & 3) ^ (R & 3));
            *(_Float16*)(rowp + pos * 16 + ((d & 7) << 1)) =
                (_Float16)(o_[nt2][r] * inv[r]);
        }
    }
}

// ---------------------------------------------------------------------------
extern "C" void kernel_launch(void* const* d_in, const int* in_sizes, int n_in,
                              void* d_out, int out_size, void* d_ws, size_t ws_size,
                              hipStream_t stream)
{
    (void)in_sizes; (void)n_in; (void)out_size; (void)ws_size;
    const float* hidden = (const float*)d_in[0];
    const float* cosb   = (const float*)d_in[1];
    const float* sinb   = (const float*)d_in[2];
    const float* Wq     = (const float*)d_in[3];
    const float* Wk     = (const float*)d_in[4];
    const float* Wv     = (const float*)d_in[5];
    const float* Wo     = (const float*)d_in[6];
    const float* qw     = (const float*)d_in[7];
    const float* kw     = (const float*)d_in[8];
    float* out = (float*)d_out;

    char* ws = (char*)d_ws;
    const size_t MB = 1ull << 20;
    float*     P     = (float*)(ws);                  // 64 MB [4096][4096]
    _Float16*  attnH = (_Float16*)(ws + 64  * MB);    // 16 MB [4096][2048]
    _Float16*  HhG   = (_Float16*)(ws + 80  * MB);    // 16 MB [4096][2048]
    _Float16*  WallH = (_Float16*)(ws + 96  * MB);    // 16 MB [4096][2048] (Wq|Wk|Wv)
    _Float16*  WoH   = (_Float16*)(ws + 112 * MB);    //  8 MB [2048][2048]
    _Float16*  KhG   = (_Float16*)(ws + 120 * MB);    //  8 MB
    _Float16*  VtG   = (_Float16*)(ws + 128 * MB);    //  8 MB -> ends 136 MB

    const dim3 blk(256);
    conv_h<<<TOK,  blk, 0, stream>>>(hidden, HhG);
    conv_h<<<2048, blk, 0, stream>>>(Wq, WallH);
    conv_h<<<1024, blk, 0, stream>>>(Wk, WallH + (size_t)2048 * HID);
    conv_h<<<1024, blk, 0, stream>>>(Wv, WallH + (size_t)3072 * HID);
    conv_h<<<2048, blk, 0, stream>>>(Wo, WoH);

    // fused QKV projection: N = 4096 (q|k|v), writes P fp32
    gemm_f16<<<dim3(32, 32), blk, 0, stream>>>(HhG, WallH, P, QKV_LD, 0);

    norm_rope<<<dim3(6, TOK), blk, 0, stream>>>(P, cosb, sinb, qw, kw, KhG);
    conv_v<<<dim3(TOK / 64, NKV), blk, 0, stream>>>(P, VtG);

    flash_f16<<<dim3(SEQ / 64, NH, BATCH), blk, 0, stream>>>(P, KhG, VtG, attnH);

    // output projection
    gemm_f16<<<dim3(16, 32), blk, 0, stream>>>(attnH, WoH, out, HID, 0);
}

// Round 5
// 339.479 us; speedup vs baseline: 13.2738x; 1.1313x over previous
//
#include <hip/hip_runtime.h>
#include <cstdint>

#define SEQ 2048
#define BATCH 2
#define TOK 4096
#define HID 2048
#define NH 16
#define NKV 8
#define HD 128
#define QKV_LD 4096

using f16x8 = __attribute__((ext_vector_type(8))) _Float16;
using f32x4 = __attribute__((ext_vector_type(4))) float;

#define MFMA(a, b, c) __builtin_amdgcn_mfma_f32_16x16x32_f16(a, b, c, 0, 0, 0)

__device__ inline void gload16(const void* g, void* l) {
    __builtin_amdgcn_global_load_lds(
        (const __attribute__((address_space(1))) unsigned*)g,
        (__attribute__((address_space(3))) unsigned*)l, 16, 0, 0);
}

// ---------------------------------------------------------------------------
// conv_h: fp32 [R][2048] -> fp16 [R][2048], 16B chunks swizzled within 64B
// groups: pos = (g & ~3) | ((g&3) ^ (row&3)). One block per row.
// ---------------------------------------------------------------------------
__global__ __launch_bounds__(256) void conv_h(
    const float* __restrict__ X, _Float16* __restrict__ Y)
{
    const int row = blockIdx.x;
    const int g   = threadIdx.x;            // chunk 0..255
    const float* src = X + (size_t)row * HID + g * 8;
    float4 a = *(const float4*)src;
    float4 b = *(const float4*)(src + 4);
    f16x8 v;
    v[0] = (_Float16)a.x; v[1] = (_Float16)a.y;
    v[2] = (_Float16)a.z; v[3] = (_Float16)a.w;
    v[4] = (_Float16)b.x; v[5] = (_Float16)b.y;
    v[6] = (_Float16)b.z; v[7] = (_Float16)b.w;
    const int pos = (g & ~3) | ((g & 3) ^ (row & 3));
    *(f16x8*)((char*)Y + (size_t)row * 4096 + pos * 16) = v;
}

// ---------------------------------------------------------------------------
// gemm_f16: C[m][coff+n] = sum_k A[m][k]*B[n][k], fp16 MFMA, fp32 accum/out.
// Tile 128x128, BK=32, 256 thr = 4 waves. global_load_lds staging.
// ---------------------------------------------------------------------------
__global__ __launch_bounds__(256) void gemm_f16(
    const _Float16* __restrict__ Ag, const _Float16* __restrict__ Bg,
    float* __restrict__ C, int ldc, int coff)
{
    __shared__ char ldsA[8192], ldsB[8192];   // [128 rows][64 B]

    const int tid = threadIdx.x;
    const int wv = tid >> 6, ln = tid & 63;
    const int wm = wv >> 1, wn = wv & 1;
    const int lr = ln & 15, lq = ln >> 4;
    const int bn = blockIdx.x, bm = blockIdx.y;

    f32x4 acc[4][4] = {};
    const size_t arow0 = (size_t)bm * 128;
    const size_t brow0 = (size_t)bn * 128;

    for (int k0 = 0; k0 < HID; k0 += 32) {
#pragma unroll
        for (int r = 0; r < 2; ++r) {
            const int idx = r * 256 + tid;
            const int row = idx >> 2;          // 0..127
            const int ch  = tid & 3;
            const size_t ga = ((arow0 + row) * (size_t)HID + k0) * 2 + ch * 16;
            const size_t gb = ((brow0 + row) * (size_t)HID + k0) * 2 + ch * 16;
            const int dst = (r * 256 + wv * 64) * 16;   // wave-uniform base
            gload16((const char*)Ag + ga, ldsA + dst);
            gload16((const char*)Bg + gb, ldsB + dst);
        }
        __syncthreads();

        f16x8 a[4], b[4];
#pragma unroll
        for (int i = 0; i < 4; ++i) {
            const int ra = wm * 64 + i * 16 + lr;
            a[i] = *(f16x8*)&ldsA[ra * 64 + ((lq ^ (ra & 3)) << 4)];
            const int rb = wn * 64 + i * 16 + lr;
            b[i] = *(f16x8*)&ldsB[rb * 64 + ((lq ^ (rb & 3)) << 4)];
        }
#pragma unroll
        for (int i = 0; i < 4; ++i)
#pragma unroll
            for (int j = 0; j < 4; ++j)
                acc[i][j] = MFMA(a[i], b[j], acc[i][j]);
        __syncthreads();
    }

    float* Cb = C + arow0 * ldc + coff + bn * 128;
#pragma unroll
    for (int i = 0; i < 4; ++i)
#pragma unroll
        for (int j = 0; j < 4; ++j)
#pragma unroll
            for (int r = 0; r < 4; ++r)
                Cb[(size_t)(wm * 64 + i * 16 + lq * 4 + r) * ldc
                   + wn * 64 + j * 16 + lr] = acc[i][j][r];
}

// ---------------------------------------------------------------------------
// norm_rope: q heads -> in-place fp32 in P; k heads -> RMS+RoPE then fp16,
// written pre-swizzled to KhG [b][kv][s][128] (16 chunks/row, chunk ^= s&7).
// ---------------------------------------------------------------------------
__global__ __launch_bounds__(256) void norm_rope(
    float* __restrict__ P, const float* __restrict__ cosb,
    const float* __restrict__ sinb, const float* __restrict__ qw,
    const float* __restrict__ kw, _Float16* __restrict__ KhG)
{
    const int t    = blockIdx.y;
    const int wave = threadIdx.x >> 6;
    const int lane = threadIdx.x & 63;
    const int hid  = blockIdx.x * 4 + wave; // 0..23

    float* ptr;
    const float* w;
    if (hid < NH) { ptr = P + (size_t)t * QKV_LD + hid * HD;              w = qw; }
    else          { ptr = P + (size_t)t * QKV_LD + HID + (hid - NH) * HD; w = kw; }

    float x1 = ptr[lane];
    float x2 = ptr[lane + 64];
    float ss = x1 * x1 + x2 * x2;
#pragma unroll
    for (int off = 1; off < 64; off <<= 1) ss += __shfl_xor(ss, off);
    const float r = rsqrtf(ss * (1.f / 128.f) + 1e-6f);
    const float n1 = x1 * r * w[lane];
    const float n2 = x2 * r * w[lane + 64];

    const float* cp = cosb + (size_t)t * HD;
    const float* sp = sinb + (size_t)t * HD;
    const float o1 = n1 * cp[lane]      - n2 * sp[lane];
    const float o2 = n2 * cp[lane + 64] + n1 * sp[lane + 64];

    if (hid < NH) {
        ptr[lane]      = o1;
        ptr[lane + 64] = o2;
    } else {
        const int b = t / SEQ, s = t % SEQ, kv = hid - NH;
        char* ph = (char*)KhG + ((size_t)(b * NKV + kv) * SEQ + s) * 256;
        const int s7 = s & 7;
        const int d1 = lane, d2 = lane + 64;
        *(_Float16*)(ph + (((d1 >> 3) ^ s7) << 4) + ((d1 & 7) << 1)) = (_Float16)o1;
        *(_Float16*)(ph + (((d2 >> 3) ^ s7) << 4) + ((d2 & 7) << 1)) = (_Float16)o2;
    }
}

// ---------------------------------------------------------------------------
// conv_v: V fp32 rows of P -> transposed fp16 VtG [b][kv][d=128][s=2048],
// pre-swizzled (8 chunks per 64-key group, chunk ^= d&7).
// ---------------------------------------------------------------------------
__global__ __launch_bounds__(256) void conv_v(
    const float* __restrict__ P, _Float16* __restrict__ VtG)
{
    __shared__ float Ts[64][133];
    const int kb = blockIdx.x;      // 64-token block over TOK
    const int kv = blockIdx.y;
    const int tid = threadIdx.x;

#pragma unroll
    for (int r = 0; r < 8; ++r) {
        const int idx = tid + r * 256;
        const int row = idx >> 5, c4 = (idx & 31) * 4;
        float4 v = *(const float4*)(P + (size_t)(kb * 64 + row) * QKV_LD
                                    + HID + NKV * HD + kv * HD + c4);
        Ts[row][c4 + 0] = v.x; Ts[row][c4 + 1] = v.y;
        Ts[row][c4 + 2] = v.z; Ts[row][c4 + 3] = v.w;
    }
    __syncthreads();

    const int b  = (kb * 64) / SEQ;
    const int s0 = (kb * 64) % SEQ;
#pragma unroll
    for (int w = 0; w < 4; ++w) {
        const int idx = tid + w * 256;      // 0..1023
        const int d = idx >> 3, c = idx & 7;
        f16x8 pk;
#pragma unroll
        for (int kk = 0; kk < 8; ++kk) pk[kk] = (_Float16)Ts[c * 8 + kk][d];
        char* dst = (char*)VtG + ((size_t)(b * NKV + kv) * 128 + d) * 4096
                    + ((s0 >> 3) + (c ^ (d & 7))) * 16;
        *(f16x8*)dst = pk;
    }
}

// ---------------------------------------------------------------------------
// flash_f16: MFMA flash attention, static-bias softmax (no online max —
// |s| <= 128*scale = 11.31 by Cauchy-Schwarz after RMS-norm; p = e^(s-3)
// bounded by e^8.31 < fp16 max). exp folded to a single v_exp_f32 via
// log2e pre-scaling of Q and bias in the MFMA accumulator init.
// 2-phase double-buffered K/V staging via global_load_lds.
// ---------------------------------------------------------------------------
__global__ __launch_bounds__(256) void flash_f16(
    const float* __restrict__ P, const _Float16* __restrict__ KhG,
    const _Float16* __restrict__ VtG, _Float16* __restrict__ OH)
{
    __shared__ char KhL[2][16384], VtL[2][16384];
    __shared__ _Float16 Pl[4][16][72];

    const int qt = blockIdx.x, h = blockIdx.y, b = blockIdx.z;
    const int hkv = h >> 1;
    const int tid = threadIdx.x, wv = tid >> 6, ln = tid & 63;
    const int lr = ln & 15, lq = ln >> 4;
    const int qbase = qt * 64 + wv * 16;
    const float qscale = 0.08838834764831845f * 1.4426950408889634f; // scale*log2e
    const float BIAS = 3.0f * 1.4426950408889634f;                   // 3*log2e

    f16x8 qh[4];
    {
        const float* qp = P + (size_t)(b * SEQ + qbase + lr) * QKV_LD + h * HD + lq * 8;
#pragma unroll
        for (int kc = 0; kc < 4; ++kc) {
            float4 x = *(const float4*)(qp + kc * 32);
            float4 y = *(const float4*)(qp + kc * 32 + 4);
            qh[kc][0] = (_Float16)(x.x * qscale); qh[kc][1] = (_Float16)(x.y * qscale);
            qh[kc][2] = (_Float16)(x.z * qscale); qh[kc][3] = (_Float16)(x.w * qscale);
            qh[kc][4] = (_Float16)(y.x * qscale); qh[kc][5] = (_Float16)(y.y * qscale);
            qh[kc][6] = (_Float16)(y.z * qscale); qh[kc][7] = (_Float16)(y.w * qscale);
        }
    }

    f32x4 o_[8] = {};
    float rs[4] = {0.f, 0.f, 0.f, 0.f};

    const size_t krow = (size_t)(b * NKV + hkv) * SEQ;   // 256B rows
    const size_t vrow = (size_t)(b * NKV + hkv) * 128;   // 4096B rows

    // per-lane global staging addresses (tile 0); K advances 16384B/tile,
    // V advances 128B/tile. LDS dst is linear: base + lane*16.
    const char* kg[4];
    const char* vg[4];
    int dofs[4];
#pragma unroll
    for (int r = 0; r < 4; ++r) {
        const int idx = tid + r * 256;
        kg[r] = (const char*)KhG + (krow + (idx >> 4)) * 256 + (idx & 15) * 16;
        vg[r] = (const char*)VtG + (vrow + (idx >> 3)) * 4096 + (idx & 7) * 16;
        dofs[r] = (r * 256 + wv * 64) * 16;
    }

#define STAGE(buf, kt)                                                        \
    {                                                                         \
        _Pragma("unroll")                                                     \
        for (int r = 0; r < 4; ++r) {                                         \
            gload16(kg[r] + (size_t)(kt) * 16384, &KhL[buf][dofs[r]]);        \
            gload16(vg[r] + (kt) * 128,           &VtL[buf][dofs[r]]);        \
        }                                                                     \
    }

    STAGE(0, 0);
    __syncthreads();            // drains vmcnt(0) + barrier

    int buf = 0;
    for (int kt = 0; kt < SEQ / 64; ++kt) {
        if (kt + 1 < SEQ / 64) STAGE(buf ^ 1, kt + 1);   // prefetch next tile

        // QK^T: S[16 q][64 keys]; acc pre-biased by -3*log2e
        f32x4 s[4];
#pragma unroll
        for (int nt = 0; nt < 4; ++nt) {
            const int key = nt * 16 + lr;
            f32x4 sa = {-BIAS, -BIAS, -BIAS, -BIAS};
#pragma unroll
            for (int kc = 0; kc < 4; ++kc) {
                f16x8 kh = *(f16x8*)(&KhL[buf][key * 256 +
                                     ((((kc * 4 + lq) ^ (lr & 7))) << 4)]);
                sa = MFMA(qh[kc], kh, sa);
            }
            s[nt] = sa;
        }

        // p = 2^s = e^(s_true - 3); accumulate partial row sums; to LDS
#pragma unroll
        for (int nt = 0; nt < 4; ++nt)
#pragma unroll
            for (int r = 0; r < 4; ++r) {
                const float p = exp2f(s[nt][r]);
                rs[r] += p;
                Pl[wv][lq * 4 + r][nt * 16 + lr] = (_Float16)p;
            }
        f16x8 pa0 = *(f16x8*)&Pl[wv][lr][lq * 8];
        f16x8 pa1 = *(f16x8*)&Pl[wv][lr][32 + lq * 8];

        // PV accumulate
#pragma unroll
        for (int nt2 = 0; nt2 < 8; ++nt2) {
            const int d0 = nt2 * 16 + lr;
            f16x8 v0 = *(f16x8*)(&VtL[buf][d0 * 128 + ((lq ^ (lr & 7)) << 4)]);
            f16x8 v1 = *(f16x8*)(&VtL[buf][d0 * 128 + (((4 + lq) ^ (lr & 7)) << 4)]);
            o_[nt2] = MFMA(pa0, v0, o_[nt2]);
            o_[nt2] = MFMA(pa1, v1, o_[nt2]);
        }
        __syncthreads();        // drains next-tile loads; guards buf reuse
        buf ^= 1;
    }

    // one-time cross-lane row-sum reduce (lanes sharing a row differ in lr)
    float inv[4];
#pragma unroll
    for (int r = 0; r < 4; ++r) {
        float v = rs[r];
        v += __shfl_xor(v, 1);
        v += __shfl_xor(v, 2);
        v += __shfl_xor(v, 4);
        v += __shfl_xor(v, 8);
        inv[r] = 1.0f / v;
    }

    // write fp16, pre-swizzled for gemm_f16 (chunk ^= row&3 within 64B groups)
#pragma unroll
    for (int r = 0; r < 4; ++r) {
        const int R = b * SEQ + qbase + lq * 4 + r;
        char* rowp = (char*)OH + (size_t)R * 4096;
#pragma unroll
        for (int nt2 = 0; nt2 < 8; ++nt2) {
            const int d = h * HD + nt2 * 16 + lr;
            const int g = d >> 3;
            const int pos = (g & ~3) | ((g & 3) ^ (R & 3));
            *(_Float16*)(rowp + pos * 16 + ((d & 7) << 1)) =
                (_Float16)(o_[nt2][r] * inv[r]);
        }
    }
#undef STAGE
}

// ---------------------------------------------------------------------------
extern "C" void kernel_launch(void* const* d_in, const int* in_sizes, int n_in,
                              void* d_out, int out_size, void* d_ws, size_t ws_size,
                              hipStream_t stream)
{
    (void)in_sizes; (void)n_in; (void)out_size; (void)ws_size;
    const float* hidden = (const float*)d_in[0];
    const float* cosb   = (const float*)d_in[1];
    const float* sinb   = (const float*)d_in[2];
    const float* Wq     = (const float*)d_in[3];
    const float* Wk     = (const float*)d_in[4];
    const float* Wv     = (const float*)d_in[5];
    const float* Wo     = (const float*)d_in[6];
    const float* qw     = (const float*)d_in[7];
    const float* kw     = (const float*)d_in[8];
    float* out = (float*)d_out;

    char* ws = (char*)d_ws;
    const size_t MB = 1ull << 20;
    float*     P     = (float*)(ws);                  // 64 MB [4096][4096]
    _Float16*  attnH = (_Float16*)(ws + 64  * MB);    // 16 MB [4096][2048]
    _Float16*  HhG   = (_Float16*)(ws + 80  * MB);    // 16 MB [4096][2048]
    _Float16*  WallH = (_Float16*)(ws + 96  * MB);    // 16 MB [4096][2048] (Wq|Wk|Wv)
    _Float16*  WoH   = (_Float16*)(ws + 112 * MB);    //  8 MB [2048][2048]
    _Float16*  KhG   = (_Float16*)(ws + 120 * MB);    //  8 MB
    _Float16*  VtG   = (_Float16*)(ws + 128 * MB);    //  8 MB -> ends 136 MB

    const dim3 blk(256);
    conv_h<<<TOK,  blk, 0, stream>>>(hidden, HhG);
    conv_h<<<2048, blk, 0, stream>>>(Wq, WallH);
    conv_h<<<1024, blk, 0, stream>>>(Wk, WallH + (size_t)2048 * HID);
    conv_h<<<1024, blk, 0, stream>>>(Wv, WallH + (size_t)3072 * HID);
    conv_h<<<2048, blk, 0, stream>>>(Wo, WoH);

    // fused QKV projection: N = 4096 (q|k|v), writes P fp32
    gemm_f16<<<dim3(32, 32), blk, 0, stream>>>(HhG, WallH, P, QKV_LD, 0);

    norm_rope<<<dim3(6, TOK), blk, 0, stream>>>(P, cosb, sinb, qw, kw, KhG);
    conv_v<<<dim3(TOK / 64, NKV), blk, 0, stream>>>(P, VtG);

    flash_f16<<<dim3(SEQ / 64, NH, BATCH), blk, 0, stream>>>(P, KhG, VtG, attnH);

    // output projection
    gemm_f16<<<dim3(16, 32), blk, 0, stream>>>(attnH, WoH, out, HID, 0);
}

// Round 6
// 303.793 us; speedup vs baseline: 14.8331x; 1.1175x over previous
//
#include <hip/hip_runtime.h>
#include <cstdint>

#define SEQ 2048
#define BATCH 2
#define TOK 4096
#define HID 2048
#define NH 16
#define NKV 8
#define HD 128
#define QKV_LD 4096

using f16x8 = __attribute__((ext_vector_type(8))) _Float16;
using f32x4 = __attribute__((ext_vector_type(4))) float;

#define MFMA(a, b, c) __builtin_amdgcn_mfma_f32_16x16x32_f16(a, b, c, 0, 0, 0)

__device__ inline void gload16(const void* g, void* l) {
    __builtin_amdgcn_global_load_lds(
        (const __attribute__((address_space(1))) unsigned*)g,
        (__attribute__((address_space(3))) unsigned*)l, 16, 0, 0);
}

// ---------------------------------------------------------------------------
// conv_h: fp32 [R][2048] -> fp16 [R][2048], 16B chunks swizzled within 64B
// groups: pos = (g & ~3) | ((g&3) ^ (row&3)). One block per row.
// ---------------------------------------------------------------------------
__global__ __launch_bounds__(256) void conv_h(
    const float* __restrict__ X, _Float16* __restrict__ Y)
{
    const int row = blockIdx.x;
    const int g   = threadIdx.x;            // chunk 0..255
    const float* src = X + (size_t)row * HID + g * 8;
    float4 a = *(const float4*)src;
    float4 b = *(const float4*)(src + 4);
    f16x8 v;
    v[0] = (_Float16)a.x; v[1] = (_Float16)a.y;
    v[2] = (_Float16)a.z; v[3] = (_Float16)a.w;
    v[4] = (_Float16)b.x; v[5] = (_Float16)b.y;
    v[6] = (_Float16)b.z; v[7] = (_Float16)b.w;
    const int pos = (g & ~3) | ((g & 3) ^ (row & 3));
    *(f16x8*)((char*)Y + (size_t)row * 4096 + pos * 16) = v;
}

// ---------------------------------------------------------------------------
// gemm_f16: C[m][coff+n] = sum_k A[m][k]*B[n][k], fp16 MFMA, fp32 accum/out.
// Tile 128x128, BK=32, 256 thr = 4 waves. global_load_lds staging.
// ---------------------------------------------------------------------------
__global__ __launch_bounds__(256) void gemm_f16(
    const _Float16* __restrict__ Ag, const _Float16* __restrict__ Bg,
    float* __restrict__ C, int ldc, int coff)
{
    __shared__ char ldsA[8192], ldsB[8192];   // [128 rows][64 B]

    const int tid = threadIdx.x;
    const int wv = tid >> 6, ln = tid & 63;
    const int wm = wv >> 1, wn = wv & 1;
    const int lr = ln & 15, lq = ln >> 4;
    const int bn = blockIdx.x, bm = blockIdx.y;

    f32x4 acc[4][4] = {};
    const size_t arow0 = (size_t)bm * 128;
    const size_t brow0 = (size_t)bn * 128;

    for (int k0 = 0; k0 < HID; k0 += 32) {
#pragma unroll
        for (int r = 0; r < 2; ++r) {
            const int idx = r * 256 + tid;
            const int row = idx >> 2;          // 0..127
            const int ch  = tid & 3;
            const size_t ga = ((arow0 + row) * (size_t)HID + k0) * 2 + ch * 16;
            const size_t gb = ((brow0 + row) * (size_t)HID + k0) * 2 + ch * 16;
            const int dst = (r * 256 + wv * 64) * 16;   // wave-uniform base
            gload16((const char*)Ag + ga, ldsA + dst);
            gload16((const char*)Bg + gb, ldsB + dst);
        }
        __syncthreads();

        f16x8 a[4], b[4];
#pragma unroll
        for (int i = 0; i < 4; ++i) {
            const int ra = wm * 64 + i * 16 + lr;
            a[i] = *(f16x8*)&ldsA[ra * 64 + ((lq ^ (ra & 3)) << 4)];
            const int rb = wn * 64 + i * 16 + lr;
            b[i] = *(f16x8*)&ldsB[rb * 64 + ((lq ^ (rb & 3)) << 4)];
        }
#pragma unroll
        for (int i = 0; i < 4; ++i)
#pragma unroll
            for (int j = 0; j < 4; ++j)
                acc[i][j] = MFMA(a[i], b[j], acc[i][j]);
        __syncthreads();
    }

    float* Cb = C + arow0 * ldc + coff + bn * 128;
#pragma unroll
    for (int i = 0; i < 4; ++i)
#pragma unroll
        for (int j = 0; j < 4; ++j)
#pragma unroll
            for (int r = 0; r < 4; ++r)
                Cb[(size_t)(wm * 64 + i * 16 + lq * 4 + r) * ldc
                   + wn * 64 + j * 16 + lr] = acc[i][j][r];
}

// ---------------------------------------------------------------------------
// norm_rope: q heads -> in-place fp32 in P; k heads -> RMS+RoPE then fp16,
// written pre-swizzled to KhG [b][kv][s][128] (16 chunks/row, chunk ^= s&7).
// ---------------------------------------------------------------------------
__global__ __launch_bounds__(256) void norm_rope(
    float* __restrict__ P, const float* __restrict__ cosb,
    const float* __restrict__ sinb, const float* __restrict__ qw,
    const float* __restrict__ kw, _Float16* __restrict__ KhG)
{
    const int t    = blockIdx.y;
    const int wave = threadIdx.x >> 6;
    const int lane = threadIdx.x & 63;
    const int hid  = blockIdx.x * 4 + wave; // 0..23

    float* ptr;
    const float* w;
    if (hid < NH) { ptr = P + (size_t)t * QKV_LD + hid * HD;              w = qw; }
    else          { ptr = P + (size_t)t * QKV_LD + HID + (hid - NH) * HD; w = kw; }

    float x1 = ptr[lane];
    float x2 = ptr[lane + 64];
    float ss = x1 * x1 + x2 * x2;
#pragma unroll
    for (int off = 1; off < 64; off <<= 1) ss += __shfl_xor(ss, off);
    const float r = rsqrtf(ss * (1.f / 128.f) + 1e-6f);
    const float n1 = x1 * r * w[lane];
    const float n2 = x2 * r * w[lane + 64];

    const float* cp = cosb + (size_t)t * HD;
    const float* sp = sinb + (size_t)t * HD;
    const float o1 = n1 * cp[lane]      - n2 * sp[lane];
    const float o2 = n2 * cp[lane + 64] + n1 * sp[lane + 64];

    if (hid < NH) {
        ptr[lane]      = o1;
        ptr[lane + 64] = o2;
    } else {
        const int b = t / SEQ, s = t % SEQ, kv = hid - NH;
        char* ph = (char*)KhG + ((size_t)(b * NKV + kv) * SEQ + s) * 256;
        const int s7 = s & 7;
        const int d1 = lane, d2 = lane + 64;
        *(_Float16*)(ph + (((d1 >> 3) ^ s7) << 4) + ((d1 & 7) << 1)) = (_Float16)o1;
        *(_Float16*)(ph + (((d2 >> 3) ^ s7) << 4) + ((d2 & 7) << 1)) = (_Float16)o2;
    }
}

// ---------------------------------------------------------------------------
// conv_v: V fp32 rows of P -> transposed fp16 VtG [b][kv][d=128][s=2048],
// pre-swizzled (8 chunks per 64-key group, chunk ^= d&7).
// ---------------------------------------------------------------------------
__global__ __launch_bounds__(256) void conv_v(
    const float* __restrict__ P, _Float16* __restrict__ VtG)
{
    __shared__ float Ts[64][133];
    const int kb = blockIdx.x;      // 64-token block over TOK
    const int kv = blockIdx.y;
    const int tid = threadIdx.x;

#pragma unroll
    for (int r = 0; r < 8; ++r) {
        const int idx = tid + r * 256;
        const int row = idx >> 5, c4 = (idx & 31) * 4;
        float4 v = *(const float4*)(P + (size_t)(kb * 64 + row) * QKV_LD
                                    + HID + NKV * HD + kv * HD + c4);
        Ts[row][c4 + 0] = v.x; Ts[row][c4 + 1] = v.y;
        Ts[row][c4 + 2] = v.z; Ts[row][c4 + 3] = v.w;
    }
    __syncthreads();

    const int b  = (kb * 64) / SEQ;
    const int s0 = (kb * 64) % SEQ;
#pragma unroll
    for (int w = 0; w < 4; ++w) {
        const int idx = tid + w * 256;      // 0..1023
        const int d = idx >> 3, c = idx & 7;
        f16x8 pk;
#pragma unroll
        for (int kk = 0; kk < 8; ++kk) pk[kk] = (_Float16)Ts[c * 8 + kk][d];
        char* dst = (char*)VtG + ((size_t)(b * NKV + kv) * 128 + d) * 4096
                    + ((s0 >> 3) + (c ^ (d & 7))) * 16;
        *(f16x8*)dst = pk;
    }
}

// ---------------------------------------------------------------------------
// flash_f16: MFMA flash attention, static-bias softmax (p = e^(s-3), valid
// since |s| <= 128*scale = 11.31 by Cauchy-Schwarz after RMS-norm).
// 32 q-rows per wave (128 per block) to halve LDS-read per output.
// K double-buffered, V single-buffered; 2 barriers/tile, stages issued at
// iteration end so latency hides under QK+exp of the next tile.
// ---------------------------------------------------------------------------
__global__ __launch_bounds__(256) void flash_f16(
    const float* __restrict__ P, const _Float16* __restrict__ KhG,
    const _Float16* __restrict__ VtG, _Float16* __restrict__ OH)
{
    __shared__ char KhL[2][16384];          // [key 64][chunk^swz 16]*16B
    __shared__ char VtL[16384];             // [d 128][chunk^swz 8]*16B
    __shared__ _Float16 Pl[4][32][72];      // per-wave P tile [q][key]

    const int qt = blockIdx.x, h = blockIdx.y, b = blockIdx.z;
    const int hkv = h >> 1;
    const int tid = threadIdx.x, wv = tid >> 6, ln = tid & 63;
    const int lr = ln & 15, lq = ln >> 4;
    const int qbase = qt * 128 + wv * 32;
    const float qscale = 0.08838834764831845f * 1.4426950408889634f; // scale*log2e
    const float BIAS = 3.0f * 1.4426950408889634f;                   // 3*log2e

    // Q fragments: 2 m-tiles x 4 k-chunks, pre-scaled by scale*log2e
    f16x8 qh[2][4];
#pragma unroll
    for (int mi = 0; mi < 2; ++mi) {
        const float* qp = P + (size_t)(b * SEQ + qbase + mi * 16 + lr) * QKV_LD
                          + h * HD + lq * 8;
#pragma unroll
        for (int kc = 0; kc < 4; ++kc) {
            float4 x = *(const float4*)(qp + kc * 32);
            float4 y = *(const float4*)(qp + kc * 32 + 4);
            qh[mi][kc][0] = (_Float16)(x.x * qscale); qh[mi][kc][1] = (_Float16)(x.y * qscale);
            qh[mi][kc][2] = (_Float16)(x.z * qscale); qh[mi][kc][3] = (_Float16)(x.w * qscale);
            qh[mi][kc][4] = (_Float16)(y.x * qscale); qh[mi][kc][5] = (_Float16)(y.y * qscale);
            qh[mi][kc][6] = (_Float16)(y.z * qscale); qh[mi][kc][7] = (_Float16)(y.w * qscale);
        }
    }

    f32x4 o_[2][8] = {};
    float rs[2][4] = {};

    const size_t krow = (size_t)(b * NKV + hkv) * SEQ;   // 256B rows
    const size_t vrow = (size_t)(b * NKV + hkv) * 128;   // 4096B rows

    // per-lane global staging addresses (tile 0); K +16384B/tile, V +128B/tile
    const char* kg[4];
    const char* vg[4];
    int dofs[4];
#pragma unroll
    for (int r = 0; r < 4; ++r) {
        const int idx = tid + r * 256;
        kg[r] = (const char*)KhG + (krow + (idx >> 4)) * 256 + (idx & 15) * 16;
        vg[r] = (const char*)VtG + (vrow + (idx >> 3)) * 4096 + (idx & 7) * 16;
        dofs[r] = (r * 256 + wv * 64) * 16;
    }

#define STAGE_K(buf, kt)                                                      \
    {                                                                         \
        _Pragma("unroll")                                                     \
        for (int r = 0; r < 4; ++r)                                           \
            gload16(kg[r] + (size_t)(kt) * 16384, &KhL[buf][dofs[r]]);        \
    }
#define STAGE_V(kt)                                                           \
    {                                                                         \
        _Pragma("unroll")                                                     \
        for (int r = 0; r < 4; ++r)                                           \
            gload16(vg[r] + (kt) * 128, &VtL[dofs[r]]);                       \
    }

    STAGE_K(0, 0);
    STAGE_V(0);
    STAGE_K(1, 1);
    __syncthreads();            // drains vmcnt(0): K(0), V(0), K(1) ready

    const int NT = SEQ / 64;
    for (int kt = 0; kt < NT; ++kt) {
        const int buf = kt & 1;

        // QK^T: S[32 q][64 keys]; acc pre-biased by -3*log2e
        f32x4 s[2][4];
#pragma unroll
        for (int nt = 0; nt < 4; ++nt) {
            const int key = nt * 16 + lr;
            f16x8 kh[4];
#pragma unroll
            for (int kc = 0; kc < 4; ++kc)
                kh[kc] = *(f16x8*)(&KhL[buf][key * 256 +
                                   ((((kc * 4 + lq) ^ (lr & 7))) << 4)]);
#pragma unroll
            for (int mi = 0; mi < 2; ++mi) {
                f32x4 sa = {-BIAS, -BIAS, -BIAS, -BIAS};
#pragma unroll
                for (int kc = 0; kc < 4; ++kc)
                    sa = MFMA(qh[mi][kc], kh[kc], sa);
                s[mi][nt] = sa;
            }
        }

        // p = 2^s = e^(s_true - 3); partial row sums; P -> per-wave LDS
#pragma unroll
        for (int mi = 0; mi < 2; ++mi)
#pragma unroll
            for (int nt = 0; nt < 4; ++nt)
#pragma unroll
                for (int r = 0; r < 4; ++r) {
                    const float p = exp2f(s[mi][nt][r]);
                    rs[mi][r] += p;
                    Pl[wv][mi * 16 + lq * 4 + r][nt * 16 + lr] = (_Float16)p;
                }
        f16x8 pa[2][2];
#pragma unroll
        for (int mi = 0; mi < 2; ++mi) {
            pa[mi][0] = *(f16x8*)&Pl[wv][mi * 16 + lr][lq * 8];
            pa[mi][1] = *(f16x8*)&Pl[wv][mi * 16 + lr][32 + lq * 8];
        }

        __syncthreads();        // drains V(kt) (+K(kt+1) early); issued last iter

        // PV accumulate: O[32 q][128 d] += P(32x64) x V(64x128)
#pragma unroll
        for (int nt2 = 0; nt2 < 8; ++nt2) {
            const int d0 = nt2 * 16 + lr;
            f16x8 v0 = *(f16x8*)(&VtL[d0 * 128 + ((lq ^ (d0 & 7)) << 4)]);
            f16x8 v1 = *(f16x8*)(&VtL[d0 * 128 + (((4 + lq) ^ (d0 & 7)) << 4)]);
#pragma unroll
            for (int mi = 0; mi < 2; ++mi) {
                o_[mi][nt2] = MFMA(pa[mi][0], v0, o_[mi][nt2]);
                o_[mi][nt2] = MFMA(pa[mi][1], v1, o_[mi][nt2]);
            }
        }

        __syncthreads();        // all waves done with V(kt) -> safe to overwrite

        if (kt + 1 < NT) STAGE_V(kt + 1);
        if (kt + 2 < NT) STAGE_K(buf, kt + 2);
    }

    // cross-lane row-sum reduce (lanes sharing a q-row differ in lr = l&15)
    float inv[2][4];
#pragma unroll
    for (int mi = 0; mi < 2; ++mi)
#pragma unroll
        for (int r = 0; r < 4; ++r) {
            float v = rs[mi][r];
            v += __shfl_xor(v, 1);
            v += __shfl_xor(v, 2);
            v += __shfl_xor(v, 4);
            v += __shfl_xor(v, 8);
            inv[mi][r] = 1.0f / v;
        }

    // write fp16, pre-swizzled for gemm_f16 (chunk ^= row&3 within 64B groups)
#pragma unroll
    for (int mi = 0; mi < 2; ++mi)
#pragma unroll
        for (int r = 0; r < 4; ++r) {
            const int R = b * SEQ + qbase + mi * 16 + lq * 4 + r;
            char* rowp = (char*)OH + (size_t)R * 4096;
#pragma unroll
            for (int nt2 = 0; nt2 < 8; ++nt2) {
                const int d = h * HD + nt2 * 16 + lr;
                const int g = d >> 3;
                const int pos = (g & ~3) | ((g & 3) ^ (R & 3));
                *(_Float16*)(rowp + pos * 16 + ((d & 7) << 1)) =
                    (_Float16)(o_[mi][nt2][r] * inv[mi][r]);
            }
        }
#undef STAGE_K
#undef STAGE_V
}

// ---------------------------------------------------------------------------
extern "C" void kernel_launch(void* const* d_in, const int* in_sizes, int n_in,
                              void* d_out, int out_size, void* d_ws, size_t ws_size,
                              hipStream_t stream)
{
    (void)in_sizes; (void)n_in; (void)out_size; (void)ws_size;
    const float* hidden = (const float*)d_in[0];
    const float* cosb   = (const float*)d_in[1];
    const float* sinb   = (const float*)d_in[2];
    const float* Wq     = (const float*)d_in[3];
    const float* Wk     = (const float*)d_in[4];
    const float* Wv     = (const float*)d_in[5];
    const float* Wo     = (const float*)d_in[6];
    const float* qw     = (const float*)d_in[7];
    const float* kw     = (const float*)d_in[8];
    float* out = (float*)d_out;

    char* ws = (char*)d_ws;
    const size_t MB = 1ull << 20;
    float*     P     = (float*)(ws);                  // 64 MB [4096][4096]
    _Float16*  attnH = (_Float16*)(ws + 64  * MB);    // 16 MB [4096][2048]
    _Float16*  HhG   = (_Float16*)(ws + 80  * MB);    // 16 MB [4096][2048]
    _Float16*  WallH = (_Float16*)(ws + 96  * MB);    // 16 MB [4096][2048] (Wq|Wk|Wv)
    _Float16*  WoH   = (_Float16*)(ws + 112 * MB);    //  8 MB [2048][2048]
    _Float16*  KhG   = (_Float16*)(ws + 120 * MB);    //  8 MB
    _Float16*  VtG   = (_Float16*)(ws + 128 * MB);    //  8 MB -> ends 136 MB

    const dim3 blk(256);
    conv_h<<<TOK,  blk, 0, stream>>>(hidden, HhG);
    conv_h<<<2048, blk, 0, stream>>>(Wq, WallH);
    conv_h<<<1024, blk, 0, stream>>>(Wk, WallH + (size_t)2048 * HID);
    conv_h<<<1024, blk, 0, stream>>>(Wv, WallH + (size_t)3072 * HID);
    conv_h<<<2048, blk, 0, stream>>>(Wo, WoH);

    // fused QKV projection: N = 4096 (q|k|v), writes P fp32
    gemm_f16<<<dim3(32, 32), blk, 0, stream>>>(HhG, WallH, P, QKV_LD, 0);

    norm_rope<<<dim3(6, TOK), blk, 0, stream>>>(P, cosb, sinb, qw, kw, KhG);
    conv_v<<<dim3(TOK / 64, NKV), blk, 0, stream>>>(P, VtG);

    flash_f16<<<dim3(SEQ / 128, NH, BATCH), blk, 0, stream>>>(P, KhG, VtG, attnH);

    // output projection
    gemm_f16<<<dim3(16, 32), blk, 0, stream>>>(attnH, WoH, out, HID, 0);
}

// Round 7
// 261.271 us; speedup vs baseline: 17.2471x; 1.1627x over previous
//
#include <hip/hip_runtime.h>
#include <cstdint>

#define SEQ 2048
#define BATCH 2
#define TOK 4096
#define HID 2048
#define NH 16
#define NKV 8
#define HD 128
#define QKV_LD 4096

using f16x8 = __attribute__((ext_vector_type(8))) _Float16;
using f32x4 = __attribute__((ext_vector_type(4))) float;

#define MFMA(a, b, c) __builtin_amdgcn_mfma_f32_16x16x32_f16(a, b, c, 0, 0, 0)

__device__ inline void gload16(const void* g, void* l) {
    __builtin_amdgcn_global_load_lds(
        (const __attribute__((address_space(1))) unsigned*)g,
        (__attribute__((address_space(3))) unsigned*)l, 16, 0, 0);
}

// ---------------------------------------------------------------------------
// conv_plain: fp32 [R][2048] -> fp16 [R][2048], plain row-major (the 256-GEMM
// applies its LDS swizzle via per-lane source addresses at staging time).
// ---------------------------------------------------------------------------
__global__ __launch_bounds__(256) void conv_plain(
    const float* __restrict__ X, _Float16* __restrict__ Y)
{
    const int row = blockIdx.x;
    const int gch = threadIdx.x;            // chunk 0..255
    const float* src = X + (size_t)row * HID + gch * 8;
    float4 a = *(const float4*)src;
    float4 b = *(const float4*)(src + 4);
    f16x8 v;
    v[0] = (_Float16)a.x; v[1] = (_Float16)a.y;
    v[2] = (_Float16)a.z; v[3] = (_Float16)a.w;
    v[4] = (_Float16)b.x; v[5] = (_Float16)b.y;
    v[6] = (_Float16)b.z; v[7] = (_Float16)b.w;
    *(f16x8*)((char*)Y + (size_t)row * 4096 + gch * 16) = v;
}

// ---------------------------------------------------------------------------
// gemm256: C[m][n] = sum_k A[m][k]*B[n][k], fp16 MFMA, fp32 accum/out.
// BM=BN=256, BK=64, 512 thr = 8 waves (2M x 4N), per-wave 128x64 out.
// LDS 128 KB double-buffer; one vmcnt(0)+barrier per K-tile; stages for
// tile t+1 issued right after the B-frag reads of tile t (~64 MFMAs of
// latency hiding). Bank-conflict-free via chunk ^= row&7 baked into the
// per-lane global source (linear LDS dest) and applied again on ds_read.
// ---------------------------------------------------------------------------
__global__ __launch_bounds__(512, 2) void gemm256(
    const _Float16* __restrict__ Ag, const _Float16* __restrict__ Bg,
    float* __restrict__ C, int ldc, int K)
{
    // [buf][half: A0,A1,B0,B1][128 rows][128 B]
    __shared__ char lds[2][4][16384];

    const int tid = threadIdx.x;
    const int wv = tid >> 6, ln = tid & 63;
    const int wm = wv >> 2, wn = wv & 3;
    const int lr = ln & 15, lq = ln >> 4;
    const int bn = blockIdx.x, bm = blockIdx.y;

    f32x4 acc[8][4] = {};

    const size_t arow0 = (size_t)bm * 256;
    const size_t brow0 = (size_t)bn * 256;

    // staging source offsets (bytes), XOR-swizzled per lane; +t*128 per K-tile
    const int g = tid & 7;
    uint32_t offA[2][2], offB[2][2];        // [half][issue]
#pragma unroll
    for (int i = 0; i < 2; ++i) {
        const int row = (i * 512 + tid) >> 3;            // 0..127
        const uint32_t sw = (uint32_t)((g ^ (row & 7)) << 4);
        offA[0][i] = (uint32_t)((arow0 + row) * 4096) + sw;
        offA[1][i] = (uint32_t)((arow0 + 128 + row) * 4096) + sw;
        offB[0][i] = (uint32_t)((brow0 + row) * 4096) + sw;
        offB[1][i] = (uint32_t)((brow0 + 128 + row) * 4096) + sw;
    }
    const int dst0 = wv * 64 * 16;          // wave-uniform LDS base (+i*8192)

    // ds_read swizzled chunk offsets (row&7 == lr&7 for all fragments)
    const int swz0 = ((lq ^ (lr & 7)) << 4);
    const int swz1 = (((4 + lq) ^ (lr & 7)) << 4);

#define STAGE_ALL(bufsel, t)                                                   \
    { _Pragma("unroll")                                                        \
      for (int i = 0; i < 2; ++i) {                                            \
        gload16((const char*)Ag + offA[0][i] + (size_t)(t) * 128,              \
                &lds[bufsel][0][i * 8192 + dst0]);                             \
        gload16((const char*)Ag + offA[1][i] + (size_t)(t) * 128,              \
                &lds[bufsel][1][i * 8192 + dst0]);                             \
        gload16((const char*)Bg + offB[0][i] + (size_t)(t) * 128,              \
                &lds[bufsel][2][i * 8192 + dst0]);                             \
        gload16((const char*)Bg + offB[1][i] + (size_t)(t) * 128,              \
                &lds[bufsel][3][i * 8192 + dst0]);                             \
      } }

    STAGE_ALL(0, 0);
    asm volatile("s_waitcnt vmcnt(0)" ::: "memory");
    __builtin_amdgcn_s_barrier();

    const int NT = K / 64;
    for (int t = 0; t < NT; ++t) {
        const int buf = t & 1;
        const char* Ab = &lds[buf][wm][0];
        const char* Bb = &lds[buf][2 + (wn >> 1)][(wn & 1) * 64 * 128];

        // B fragments for the whole K-tile (8 reads)
        f16x8 bfr[4][2];
#pragma unroll
        for (int nj = 0; nj < 4; ++nj) {
            bfr[nj][0] = *(const f16x8*)(Bb + (nj * 16 + lr) * 128 + swz0);
            bfr[nj][1] = *(const f16x8*)(Bb + (nj * 16 + lr) * 128 + swz1);
        }

        if (t + 1 < NT) STAGE_ALL(buf ^ 1, t + 1);   // early issue, late drain

        __builtin_amdgcn_s_setprio(1);
#pragma unroll
        for (int mi = 0; mi < 8; ++mi) {
            f16x8 a0 = *(const f16x8*)(Ab + (mi * 16 + lr) * 128 + swz0);
            f16x8 a1 = *(const f16x8*)(Ab + (mi * 16 + lr) * 128 + swz1);
#pragma unroll
            for (int nj = 0; nj < 4; ++nj) {
                acc[mi][nj] = MFMA(a0, bfr[nj][0], acc[mi][nj]);
                acc[mi][nj] = MFMA(a1, bfr[nj][1], acc[mi][nj]);
            }
        }
        __builtin_amdgcn_s_setprio(0);

        asm volatile("s_waitcnt vmcnt(0)" ::: "memory");
        __builtin_amdgcn_s_barrier();
    }
#undef STAGE_ALL

    // epilogue: fp32 C write
#pragma unroll
    for (int mi = 0; mi < 8; ++mi)
#pragma unroll
        for (int r = 0; r < 4; ++r) {
            float* rowp = C + (size_t)(arow0 + wm * 128 + mi * 16 + lq * 4 + r) * ldc
                          + brow0 + wn * 64 + lr;
#pragma unroll
            for (int nj = 0; nj < 4; ++nj)
                rowp[nj * 16] = acc[mi][nj][r];
        }
}

// ---------------------------------------------------------------------------
// norm_rope: q heads -> in-place fp32 in P; k heads -> RMS+RoPE then fp16,
// written pre-swizzled to KhG [b][kv][s][128] (16 chunks/row, chunk ^= s&7).
// ---------------------------------------------------------------------------
__global__ __launch_bounds__(256) void norm_rope(
    float* __restrict__ P, const float* __restrict__ cosb,
    const float* __restrict__ sinb, const float* __restrict__ qw,
    const float* __restrict__ kw, _Float16* __restrict__ KhG)
{
    const int t    = blockIdx.y;
    const int wave = threadIdx.x >> 6;
    const int lane = threadIdx.x & 63;
    const int hid  = blockIdx.x * 4 + wave; // 0..23

    float* ptr;
    const float* w;
    if (hid < NH) { ptr = P + (size_t)t * QKV_LD + hid * HD;              w = qw; }
    else          { ptr = P + (size_t)t * QKV_LD + HID + (hid - NH) * HD; w = kw; }

    float x1 = ptr[lane];
    float x2 = ptr[lane + 64];
    float ss = x1 * x1 + x2 * x2;
#pragma unroll
    for (int off = 1; off < 64; off <<= 1) ss += __shfl_xor(ss, off);
    const float r = rsqrtf(ss * (1.f / 128.f) + 1e-6f);
    const float n1 = x1 * r * w[lane];
    const float n2 = x2 * r * w[lane + 64];

    const float* cp = cosb + (size_t)t * HD;
    const float* sp = sinb + (size_t)t * HD;
    const float o1 = n1 * cp[lane]      - n2 * sp[lane];
    const float o2 = n2 * cp[lane + 64] + n1 * sp[lane + 64];

    if (hid < NH) {
        ptr[lane]      = o1;
        ptr[lane + 64] = o2;
    } else {
        const int b = t / SEQ, s = t % SEQ, kv = hid - NH;
        char* ph = (char*)KhG + ((size_t)(b * NKV + kv) * SEQ + s) * 256;
        const int s7 = s & 7;
        const int d1 = lane, d2 = lane + 64;
        *(_Float16*)(ph + (((d1 >> 3) ^ s7) << 4) + ((d1 & 7) << 1)) = (_Float16)o1;
        *(_Float16*)(ph + (((d2 >> 3) ^ s7) << 4) + ((d2 & 7) << 1)) = (_Float16)o2;
    }
}

// ---------------------------------------------------------------------------
// conv_v: V fp32 rows of P -> transposed fp16 VtG [b][kv][d=128][s=2048],
// pre-swizzled (8 chunks per 64-key group, chunk ^= d&7).
// ---------------------------------------------------------------------------
__global__ __launch_bounds__(256) void conv_v(
    const float* __restrict__ P, _Float16* __restrict__ VtG)
{
    __shared__ float Ts[64][133];
    const int kb = blockIdx.x;      // 64-token block over TOK
    const int kv = blockIdx.y;
    const int tid = threadIdx.x;

#pragma unroll
    for (int r = 0; r < 8; ++r) {
        const int idx = tid + r * 256;
        const int row = idx >> 5, c4 = (idx & 31) * 4;
        float4 v = *(const float4*)(P + (size_t)(kb * 64 + row) * QKV_LD
                                    + HID + NKV * HD + kv * HD + c4);
        Ts[row][c4 + 0] = v.x; Ts[row][c4 + 1] = v.y;
        Ts[row][c4 + 2] = v.z; Ts[row][c4 + 3] = v.w;
    }
    __syncthreads();

    const int b  = (kb * 64) / SEQ;
    const int s0 = (kb * 64) % SEQ;
#pragma unroll
    for (int w = 0; w < 4; ++w) {
        const int idx = tid + w * 256;      // 0..1023
        const int d = idx >> 3, c = idx & 7;
        f16x8 pk;
#pragma unroll
        for (int kk = 0; kk < 8; ++kk) pk[kk] = (_Float16)Ts[c * 8 + kk][d];
        char* dst = (char*)VtG + ((size_t)(b * NKV + kv) * 128 + d) * 4096
                    + ((s0 >> 3) + (c ^ (d & 7))) * 16;
        *(f16x8*)dst = pk;
    }
}

// ---------------------------------------------------------------------------
// flash_f16: MFMA flash attention, static-bias softmax (p = e^(s-3), valid
// since |s| <= 128*scale = 11.31 by Cauchy-Schwarz after RMS-norm).
// 32 q-rows per wave (128 per block). K dbuf, V single-buffer.
// Output written PLAIN row-major fp16 (gemm256 swizzles at staging).
// ---------------------------------------------------------------------------
__global__ __launch_bounds__(256) void flash_f16(
    const float* __restrict__ P, const _Float16* __restrict__ KhG,
    const _Float16* __restrict__ VtG, _Float16* __restrict__ OH)
{
    __shared__ char KhL[2][16384];          // [key 64][chunk^swz 16]*16B
    __shared__ char VtL[16384];             // [d 128][chunk^swz 8]*16B
    __shared__ _Float16 Pl[4][32][72];      // per-wave P tile [q][key]

    const int qt = blockIdx.x, h = blockIdx.y, b = blockIdx.z;
    const int hkv = h >> 1;
    const int tid = threadIdx.x, wv = tid >> 6, ln = tid & 63;
    const int lr = ln & 15, lq = ln >> 4;
    const int qbase = qt * 128 + wv * 32;
    const float qscale = 0.08838834764831845f * 1.4426950408889634f; // scale*log2e
    const float BIAS = 3.0f * 1.4426950408889634f;                   // 3*log2e

    f16x8 qh[2][4];
#pragma unroll
    for (int mi = 0; mi < 2; ++mi) {
        const float* qp = P + (size_t)(b * SEQ + qbase + mi * 16 + lr) * QKV_LD
                          + h * HD + lq * 8;
#pragma unroll
        for (int kc = 0; kc < 4; ++kc) {
            float4 x = *(const float4*)(qp + kc * 32);
            float4 y = *(const float4*)(qp + kc * 32 + 4);
            qh[mi][kc][0] = (_Float16)(x.x * qscale); qh[mi][kc][1] = (_Float16)(x.y * qscale);
            qh[mi][kc][2] = (_Float16)(x.z * qscale); qh[mi][kc][3] = (_Float16)(x.w * qscale);
            qh[mi][kc][4] = (_Float16)(y.x * qscale); qh[mi][kc][5] = (_Float16)(y.y * qscale);
            qh[mi][kc][6] = (_Float16)(y.z * qscale); qh[mi][kc][7] = (_Float16)(y.w * qscale);
        }
    }

    f32x4 o_[2][8] = {};
    float rs[2][4] = {};

    const size_t krow = (size_t)(b * NKV + hkv) * SEQ;   // 256B rows
    const size_t vrow = (size_t)(b * NKV + hkv) * 128;   // 4096B rows

    const char* kg[4];
    const char* vg[4];
    int dofs[4];
#pragma unroll
    for (int r = 0; r < 4; ++r) {
        const int idx = tid + r * 256;
        kg[r] = (const char*)KhG + (krow + (idx >> 4)) * 256 + (idx & 15) * 16;
        vg[r] = (const char*)VtG + (vrow + (idx >> 3)) * 4096 + (idx & 7) * 16;
        dofs[r] = (r * 256 + wv * 64) * 16;
    }

#define STAGE_K(buf, kt)                                                      \
    { _Pragma("unroll")                                                       \
      for (int r = 0; r < 4; ++r)                                             \
          gload16(kg[r] + (size_t)(kt) * 16384, &KhL[buf][dofs[r]]); }
#define STAGE_V(kt)                                                           \
    { _Pragma("unroll")                                                       \
      for (int r = 0; r < 4; ++r)                                             \
          gload16(vg[r] + (kt) * 128, &VtL[dofs[r]]); }

    STAGE_K(0, 0);
    STAGE_V(0);
    STAGE_K(1, 1);
    __syncthreads();            // drains vmcnt(0): K(0), V(0), K(1) ready

    const int NT = SEQ / 64;
    for (int kt = 0; kt < NT; ++kt) {
        const int buf = kt & 1;

        f32x4 s[2][4];
#pragma unroll
        for (int nt = 0; nt < 4; ++nt) {
            const int key = nt * 16 + lr;
            f16x8 kh[4];
#pragma unroll
            for (int kc = 0; kc < 4; ++kc)
                kh[kc] = *(f16x8*)(&KhL[buf][key * 256 +
                                   ((((kc * 4 + lq) ^ (lr & 7))) << 4)]);
#pragma unroll
            for (int mi = 0; mi < 2; ++mi) {
                f32x4 sa = {-BIAS, -BIAS, -BIAS, -BIAS};
#pragma unroll
                for (int kc = 0; kc < 4; ++kc)
                    sa = MFMA(qh[mi][kc], kh[kc], sa);
                s[mi][nt] = sa;
            }
        }

#pragma unroll
        for (int mi = 0; mi < 2; ++mi)
#pragma unroll
            for (int nt = 0; nt < 4; ++nt)
#pragma unroll
                for (int r = 0; r < 4; ++r) {
                    const float p = exp2f(s[mi][nt][r]);
                    rs[mi][r] += p;
                    Pl[wv][mi * 16 + lq * 4 + r][nt * 16 + lr] = (_Float16)p;
                }
        f16x8 pa[2][2];
#pragma unroll
        for (int mi = 0; mi < 2; ++mi) {
            pa[mi][0] = *(f16x8*)&Pl[wv][mi * 16 + lr][lq * 8];
            pa[mi][1] = *(f16x8*)&Pl[wv][mi * 16 + lr][32 + lq * 8];
        }

        __syncthreads();        // drains V(kt) (+K(kt+1) early); issued last iter

#pragma unroll
        for (int nt2 = 0; nt2 < 8; ++nt2) {
            const int d0 = nt2 * 16 + lr;
            f16x8 v0 = *(f16x8*)(&VtL[d0 * 128 + ((lq ^ (d0 & 7)) << 4)]);
            f16x8 v1 = *(f16x8*)(&VtL[d0 * 128 + (((4 + lq) ^ (d0 & 7)) << 4)]);
#pragma unroll
            for (int mi = 0; mi < 2; ++mi) {
                o_[mi][nt2] = MFMA(pa[mi][0], v0, o_[mi][nt2]);
                o_[mi][nt2] = MFMA(pa[mi][1], v1, o_[mi][nt2]);
            }
        }

        __syncthreads();        // all waves done with V(kt) -> safe to overwrite

        if (kt + 1 < NT) STAGE_V(kt + 1);
        if (kt + 2 < NT) STAGE_K(buf, kt + 2);
    }

    float inv[2][4];
#pragma unroll
    for (int mi = 0; mi < 2; ++mi)
#pragma unroll
        for (int r = 0; r < 4; ++r) {
            float v = rs[mi][r];
            v += __shfl_xor(v, 1);
            v += __shfl_xor(v, 2);
            v += __shfl_xor(v, 4);
            v += __shfl_xor(v, 8);
            inv[mi][r] = 1.0f / v;
        }

    // plain row-major fp16 output [token][2048]
#pragma unroll
    for (int mi = 0; mi < 2; ++mi)
#pragma unroll
        for (int r = 0; r < 4; ++r) {
            const int R = b * SEQ + qbase + mi * 16 + lq * 4 + r;
            _Float16* rowp = OH + (size_t)R * HID + h * HD + lr;
#pragma unroll
            for (int nt2 = 0; nt2 < 8; ++nt2)
                rowp[nt2 * 16] = (_Float16)(o_[mi][nt2][r] * inv[mi][r]);
        }
#undef STAGE_K
#undef STAGE_V
}

// ---------------------------------------------------------------------------
extern "C" void kernel_launch(void* const* d_in, const int* in_sizes, int n_in,
                              void* d_out, int out_size, void* d_ws, size_t ws_size,
                              hipStream_t stream)
{
    (void)in_sizes; (void)n_in; (void)out_size; (void)ws_size;
    const float* hidden = (const float*)d_in[0];
    const float* cosb   = (const float*)d_in[1];
    const float* sinb   = (const float*)d_in[2];
    const float* Wq     = (const float*)d_in[3];
    const float* Wk     = (const float*)d_in[4];
    const float* Wv     = (const float*)d_in[5];
    const float* Wo     = (const float*)d_in[6];
    const float* qw     = (const float*)d_in[7];
    const float* kw     = (const float*)d_in[8];
    float* out = (float*)d_out;

    char* ws = (char*)d_ws;
    const size_t MB = 1ull << 20;
    float*     P     = (float*)(ws);                  // 64 MB [4096][4096]
    _Float16*  attnH = (_Float16*)(ws + 64  * MB);    // 16 MB [4096][2048] plain
    _Float16*  HhG   = (_Float16*)(ws + 80  * MB);    // 16 MB [4096][2048] plain
    _Float16*  WallH = (_Float16*)(ws + 96  * MB);    // 16 MB [4096][2048] (Wq|Wk|Wv)
    _Float16*  WoH   = (_Float16*)(ws + 112 * MB);    //  8 MB [2048][2048] plain
    _Float16*  KhG   = (_Float16*)(ws + 120 * MB);    //  8 MB (flash-swizzled)
    _Float16*  VtG   = (_Float16*)(ws + 128 * MB);    //  8 MB (flash-swizzled)

    const dim3 blk(256);
    conv_plain<<<TOK,  blk, 0, stream>>>(hidden, HhG);
    conv_plain<<<2048, blk, 0, stream>>>(Wq, WallH);
    conv_plain<<<1024, blk, 0, stream>>>(Wk, WallH + (size_t)2048 * HID);
    conv_plain<<<1024, blk, 0, stream>>>(Wv, WallH + (size_t)3072 * HID);
    conv_plain<<<2048, blk, 0, stream>>>(Wo, WoH);

    // fused QKV projection: 256^2 tiles, grid 16x16 = 256 blocks (1/CU)
    gemm256<<<dim3(16, 16), dim3(512), 0, stream>>>(HhG, WallH, P, QKV_LD, HID);

    norm_rope<<<dim3(6, TOK), blk, 0, stream>>>(P, cosb, sinb, qw, kw, KhG);
    conv_v<<<dim3(TOK / 64, NKV), blk, 0, stream>>>(P, VtG);

    flash_f16<<<dim3(SEQ / 128, NH, BATCH), blk, 0, stream>>>(P, KhG, VtG, attnH);

    // output projection: grid 8x16 = 128 blocks
    gemm256<<<dim3(8, 16), dim3(512), 0, stream>>>(attnH, WoH, out, HID, HID);
}